// Round 1
// baseline (2530.110 us; speedup 1.0000x reference)
//
#include <hip/hip_runtime.h>
#include <math.h>

#define B_DIM 4
#define S_DIM 4096
#define C_DIM 512
#define KV_DIM 960
#define H_DIM 4

// ---------------------------------------------------------------------------
// Generic strided batched GEMM (fp32, correctness-first):
//   C[z][m][n] = alpha * sum_k A[boffA(z) + m*sa_m + k*sa_k]
//                            * B[boffB(z) + n*sb_n + k*sb_k]
// z in [0, gridDim.z); b = z / H, h = z % H; boffX = b*sX_bb + h*sX_bh.
// C is row-major [M][N] contiguous per z (stride sc_b).
// Tiles: 64x64 output, K-step 16, 256 threads, 4x4 accum per thread.
// All problem dims here are multiples of 64/16 -> no bounds checks.
// ---------------------------------------------------------------------------
__global__ __launch_bounds__(256)
void gemm_any(const float* __restrict__ A, const float* __restrict__ B,
              float* __restrict__ C,
              int M, int N, int K, int H,
              long sa_m, long sa_k, long sa_bb, long sa_bh,
              long sb_n, long sb_k, long sb_bb, long sb_bh,
              long sc_b, float alpha)
{
    const int z = blockIdx.z;
    const int bb = z / H, hh = z % H;
    A += (long)bb * sa_bb + (long)hh * sa_bh;
    B += (long)bb * sb_bb + (long)hh * sb_bh;
    C += (long)z * sc_b;

    __shared__ float As[16][64 + 1];   // [k][m]
    __shared__ float Bs[16][64 + 1];   // [k][n]

    const int m0 = blockIdx.y * 64;
    const int n0 = blockIdx.x * 64;
    const int tid = threadIdx.x;
    const int tx = tid & 15, ty = tid >> 4;

    float acc[4][4] = {};

    for (int k0 = 0; k0 < K; k0 += 16) {
        // ---- stage A tile (64 m x 16 k) ----
        if (sa_k == 1) {
            // k is contiguous in memory: read k-fastest for coalescing
            for (int idx = tid; idx < 64 * 16; idx += 256) {
                int kk = idx & 15, m = idx >> 4;
                As[kk][m] = A[(long)(m0 + m) * sa_m + (long)(k0 + kk)];
            }
        } else {
            // m (or neither) contiguous: read m-fastest
            for (int idx = tid; idx < 64 * 16; idx += 256) {
                int m = idx & 63, kk = idx >> 6;
                As[kk][m] = A[(long)(m0 + m) * sa_m + (long)(k0 + kk) * sa_k];
            }
        }
        // ---- stage B tile (64 n x 16 k) ----
        if (sb_k == 1) {
            for (int idx = tid; idx < 64 * 16; idx += 256) {
                int kk = idx & 15, n = idx >> 4;
                Bs[kk][n] = B[(long)(n0 + n) * sb_n + (long)(k0 + kk)];
            }
        } else {
            for (int idx = tid; idx < 64 * 16; idx += 256) {
                int n = idx & 63, kk = idx >> 6;
                Bs[kk][n] = B[(long)(n0 + n) * sb_n + (long)(k0 + kk) * sb_k];
            }
        }
        __syncthreads();

        #pragma unroll
        for (int kk = 0; kk < 16; ++kk) {
            float a[4], bv[4];
            #pragma unroll
            for (int i = 0; i < 4; ++i) a[i] = As[kk][ty * 4 + i];
            #pragma unroll
            for (int j = 0; j < 4; ++j) bv[j] = Bs[kk][tx * 4 + j];
            #pragma unroll
            for (int i = 0; i < 4; ++i)
                #pragma unroll
                for (int j = 0; j < 4; ++j)
                    acc[i][j] += a[i] * bv[j];
        }
        __syncthreads();
    }

    #pragma unroll
    for (int i = 0; i < 4; ++i) {
        const long m = m0 + ty * 4 + i;
        #pragma unroll
        for (int j = 0; j < 4; ++j) {
            const long n = n0 + tx * 4 + j;
            C[m * N + n] = alpha * acc[i][j];
        }
    }
}

// ---------------------------------------------------------------------------
// InstanceNorm stats: one block per (b,h); mean + rstd over C*KV elements.
// ---------------------------------------------------------------------------
__global__ __launch_bounds__(1024)
void inorm_stats(const float* __restrict__ SC, float* __restrict__ stats)
{
    const int z = blockIdx.x;  // 0..B*H-1
    const float* p = SC + (long)z * C_DIM * KV_DIM;
    const int n = C_DIM * KV_DIM;  // 491520
    float s = 0.f, s2 = 0.f;
    for (int i = threadIdx.x; i < n; i += 1024) {
        float v = p[i];
        s += v;
        s2 += v * v;
    }
    __shared__ float sh[1024];
    __shared__ float sh2[1024];
    sh[threadIdx.x] = s;
    sh2[threadIdx.x] = s2;
    __syncthreads();
    for (int off = 512; off > 0; off >>= 1) {
        if (threadIdx.x < off) {
            sh[threadIdx.x] += sh[threadIdx.x + off];
            sh2[threadIdx.x] += sh2[threadIdx.x + off];
        }
        __syncthreads();
    }
    if (threadIdx.x == 0) {
        float mean = sh[0] / n;
        float var = sh2[0] / n - mean * mean;   // biased var (InstanceNorm default)
        stats[z * 2] = mean;
        stats[z * 2 + 1] = rsqrtf(var + 1e-5f);
    }
}

// ---------------------------------------------------------------------------
// Apply instance norm affine + row softmax over KV, in place.
// One block (256 thr) per row (z, c).
// ---------------------------------------------------------------------------
__global__ __launch_bounds__(256)
void norm_softmax(float* __restrict__ SC, const float* __restrict__ stats)
{
    const long row = blockIdx.x;          // z*C + c
    const int z = (int)(row / C_DIM);
    const float mean = stats[z * 2];
    const float rstd = stats[z * 2 + 1];
    float* p = SC + row * KV_DIM;

    const int tid = threadIdx.x;
    float x[4];
    float mx = -1e30f;
    #pragma unroll
    for (int r = 0; r < 4; ++r) {
        int j = tid + r * 256;
        x[r] = (j < KV_DIM) ? (p[j] - mean) * rstd : -1e30f;
        mx = fmaxf(mx, x[r]);
    }
    __shared__ float sh[256];
    sh[tid] = mx;
    __syncthreads();
    for (int off = 128; off > 0; off >>= 1) {
        if (tid < off) sh[tid] = fmaxf(sh[tid], sh[tid + off]);
        __syncthreads();
    }
    mx = sh[0];
    __syncthreads();

    float s = 0.f;
    #pragma unroll
    for (int r = 0; r < 4; ++r) {
        int j = tid + r * 256;
        if (j < KV_DIM) { x[r] = expf(x[r] - mx); s += x[r]; }
    }
    sh[tid] = s;
    __syncthreads();
    for (int off = 128; off > 0; off >>= 1) {
        if (tid < off) sh[tid] += sh[tid + off];
        __syncthreads();
    }
    const float inv = 1.f / sh[0];
    #pragma unroll
    for (int r = 0; r < 4; ++r) {
        int j = tid + r * 256;
        if (j < KV_DIM) p[j] = x[r] * inv;
    }
}

// ---------------------------------------------------------------------------
// Ubar[b,c,k] = sum_h U[b,h,c,k]   (1/H already folded into the U GEMM alpha)
// ---------------------------------------------------------------------------
__global__ __launch_bounds__(256)
void mean_heads(const float* __restrict__ U, float* __restrict__ Ubar)
{
    const long per = (long)C_DIM * KV_DIM;
    long i = (long)blockIdx.x * 256 + threadIdx.x;
    if (i >= (long)B_DIM * per) return;
    long b = i / per, r = i - b * per;
    const float* u = U + b * H_DIM * per + r;
    Ubar[i] = u[0] + u[per] + u[2 * per] + u[3 * per];
}

// ---------------------------------------------------------------------------
extern "C" void kernel_launch(void* const* d_in, const int* in_sizes, int n_in,
                              void* d_out, int out_size, void* d_ws, size_t ws_size,
                              hipStream_t stream)
{
    const float* emb     = (const float*)d_in[0];  // [B,S,C]
    const float* emb_all = (const float*)d_in[1];  // [B,S,KV]
    const float* Wq      = (const float*)d_in[2];  // [H,C,C]
    const float* Wk      = (const float*)d_in[3];  // [H,KV,KV]
    const float* Wv      = (const float*)d_in[4];  // [H,KV,KV]
    const float* Wo      = (const float*)d_in[5];  // [C,C]
    float* out = (float*)d_out;

    float* ws = (float*)d_ws;
    const long szG  = (long)B_DIM * C_DIM * KV_DIM;          // 1,966,080
    const long szS1 = (long)B_DIM * H_DIM * C_DIM * KV_DIM;  // 7,864,320

    float* G    = ws;            // [B,C,KV]
    float* S1   = G + szG;       // [B,H,C,KV]
    float* SC   = S1 + szS1;     // [B,H,C,KV] scores -> probs (in place)
    float* stats = SC + szS1;    // [B*H][2]
    float* U    = S1;            // reuse: S1 dead after step 3
    float* Ubar = G;             // reuse: G dead after step 2
    float* W2   = SC;            // reuse: SC dead after step 5

    const dim3 blk(256);
    const long CKV = (long)C_DIM * KV_DIM;

    // 1. G[b] = emb[b]^T * emb_all[b]           (M=C, N=KV, K=S)
    {
        dim3 grid(KV_DIM / 64, C_DIM / 64, B_DIM);
        gemm_any<<<grid, blk, 0, stream>>>(emb, emb_all, G,
            C_DIM, KV_DIM, S_DIM, 1,
            /*A*/ 1, C_DIM, (long)S_DIM * C_DIM, 0,
            /*B*/ 1, KV_DIM, (long)S_DIM * KV_DIM, 0,
            CKV, 1.f);
    }
    // 2. S1[b,h] = Wq[h] * G[b]                 (M=C, N=KV, K=C)
    {
        dim3 grid(KV_DIM / 64, C_DIM / 64, B_DIM * H_DIM);
        gemm_any<<<grid, blk, 0, stream>>>(Wq, G, S1,
            C_DIM, KV_DIM, C_DIM, H_DIM,
            /*A*/ C_DIM, 1, 0, (long)C_DIM * C_DIM,
            /*B*/ 1, KV_DIM, CKV, 0,
            CKV, 1.f);
    }
    // 3. SC[b,h] = S1[b,h] * Wk[h]^T / sqrt(KV) (M=C, N=KV, K=KV)
    {
        dim3 grid(KV_DIM / 64, C_DIM / 64, B_DIM * H_DIM);
        gemm_any<<<grid, blk, 0, stream>>>(S1, Wk, SC,
            C_DIM, KV_DIM, KV_DIM, H_DIM,
            /*A*/ KV_DIM, 1, (long)H_DIM * CKV, CKV,
            /*B*/ KV_DIM, 1, 0, (long)KV_DIM * KV_DIM,
            CKV, 1.f / sqrtf((float)KV_DIM));
    }
    // 4. InstanceNorm stats + fused norm/softmax (in place on SC)
    inorm_stats<<<B_DIM * H_DIM, 1024, 0, stream>>>(SC, stats);
    norm_softmax<<<B_DIM * H_DIM * C_DIM, 256, 0, stream>>>(SC, stats);
    // 5. U[b,h] = probs[b,h] * Wv[h] * (1/H)    (M=C, N=KV, K=KV)
    {
        dim3 grid(KV_DIM / 64, C_DIM / 64, B_DIM * H_DIM);
        gemm_any<<<grid, blk, 0, stream>>>(SC, Wv, U,
            C_DIM, KV_DIM, KV_DIM, H_DIM,
            /*A*/ KV_DIM, 1, (long)H_DIM * CKV, CKV,
            /*B*/ 1, KV_DIM, 0, (long)KV_DIM * KV_DIM,
            CKV, 1.f / H_DIM);
    }
    // 6. Ubar[b] = sum_h U[b,h]
    {
        long total = szG;
        mean_heads<<<(unsigned)((total + 255) / 256), blk, 0, stream>>>(U, Ubar);
    }
    // 7. W2[b] = Wo * Ubar[b]                   (M=C, N=KV, K=C)
    {
        dim3 grid(KV_DIM / 64, C_DIM / 64, B_DIM);
        gemm_any<<<grid, blk, 0, stream>>>(Wo, Ubar, W2,
            C_DIM, KV_DIM, C_DIM, 1,
            /*A*/ C_DIM, 1, 0, 0,
            /*B*/ 1, KV_DIM, CKV, 0,
            CKV, 1.f);
    }
    // 8. out[b] = emb_all[b] * W2[b]^T          (M=S, N=C, K=KV)
    {
        dim3 grid(C_DIM / 64, S_DIM / 64, B_DIM);
        gemm_any<<<grid, blk, 0, stream>>>(emb_all, W2, out,
            S_DIM, C_DIM, KV_DIM, 1,
            /*A*/ KV_DIM, 1, (long)S_DIM * KV_DIM, 0,
            /*B*/ KV_DIM, 1, CKV, 0,
            (long)S_DIM * C_DIM, 1.f);
    }
}

// Round 2
// 313.862 us; speedup vs baseline: 8.0612x; 8.0612x over previous
//
#include <hip/hip_runtime.h>
#include <math.h>

typedef __attribute__((ext_vector_type(8))) short short8;
typedef __attribute__((ext_vector_type(4))) float f32x4;

#define Bz 4L
#define Sz 4096L
#define Cz 512L
#define KVz 960L
#define KVP 1024L
#define Hz 4L

__device__ __forceinline__ unsigned short f2bf(float f) {
    unsigned int u; __builtin_memcpy(&u, &f, 4);
    unsigned int r = (u + 0x7FFFu + ((u >> 16) & 1u)) >> 16;
    return (unsigned short)r;
}
__device__ __forceinline__ float bf2f(unsigned short h) {
    unsigned int u = ((unsigned int)h) << 16;
    float f; __builtin_memcpy(&f, &u, 4); return f;
}
__device__ __forceinline__ void gl2lds16(const unsigned short* g, unsigned short* l) {
    __builtin_amdgcn_global_load_lds(
        (const __attribute__((address_space(1))) unsigned int*)g,
        (__attribute__((address_space(3))) unsigned int*)l, 16, 0, 0);
}

// ---------------------------------------------------------------------------
// bf16 MFMA GEMM, m97 structure. C[m][n] = alpha * sum_k A[m,k]*B[n,k].
// A,B bf16 (bits in ushort), k-contiguous (lda/ldb = row strides).
// Tile 128x128, BK=32, 256 threads = 4 waves (2x2 of 64x64).
// M,N multiples of 128; K multiple of 32. z: bb=z/H, hh=z%H offsets.
// ---------------------------------------------------------------------------
template<typename OutT>
__global__ __launch_bounds__(256)
void gemm_bt(const unsigned short* __restrict__ A, const unsigned short* __restrict__ B,
             OutT* __restrict__ C, int K, long lda, long ldb, long ldc,
             long sa_bb, long sa_bh, long sb_bb, long sb_bh, long sc_z,
             int H, float alpha)
{
    __shared__ unsigned short As[128 * 32];
    __shared__ unsigned short Bs[128 * 32];

    const int z = blockIdx.z;
    const int bb = z / H, hh = z - bb * H;
    A += (long)bb * sa_bb + (long)hh * sa_bh;
    B += (long)bb * sb_bb + (long)hh * sb_bh;
    C += (long)z * sc_z;

    const int tid  = threadIdx.x;
    const int lane = tid & 63;
    const int wave = tid >> 6;
    const int wr = wave >> 1, wc = wave & 1;

    const long m0 = (long)blockIdx.y * 128;
    const long n0 = (long)blockIdx.x * 128;

    // staging: wave handles chunks (2w, 2w+1); chunk = 16 rows x 32 k (1 KiB)
    const int ch0  = wave * 2;
    const int lrow = lane >> 2;         // 0..15
    const int lcol = (lane & 3) * 8;    // k-elem offset
    const unsigned short* ga0 = A + (m0 + ch0 * 16 + lrow) * lda + lcol;
    const unsigned short* ga1 = ga0 + 16 * lda;
    const unsigned short* gb0 = B + (n0 + ch0 * 16 + lrow) * ldb + lcol;
    const unsigned short* gb1 = gb0 + 16 * ldb;
    unsigned short* la0 = &As[ch0 * 512];
    unsigned short* la1 = &As[ch0 * 512 + 512];
    unsigned short* lb0 = &Bs[ch0 * 512];
    unsigned short* lb1 = &Bs[ch0 * 512 + 512];

    // fragment read addresses
    const int fr = lane & 15;
    const int fk = (lane >> 4) * 8;
    const unsigned short* ra = &As[(wr * 64 + fr) * 32 + fk];
    const unsigned short* rb = &Bs[(wc * 64 + fr) * 32 + fk];

    f32x4 acc[4][4];
    const f32x4 zero4 = {0.f, 0.f, 0.f, 0.f};
    #pragma unroll
    for (int i = 0; i < 4; ++i)
        #pragma unroll
        for (int j = 0; j < 4; ++j) acc[i][j] = zero4;

    for (int k0 = 0; k0 < K; k0 += 32) {
        gl2lds16(ga0, la0); gl2lds16(ga1, la1);
        gl2lds16(gb0, lb0); gl2lds16(gb1, lb1);
        ga0 += 32; ga1 += 32; gb0 += 32; gb1 += 32;
        __syncthreads();

        short8 af[4], bfr[4];
        #pragma unroll
        for (int i = 0; i < 4; ++i) af[i]  = *(const short8*)(ra + i * 512);
        #pragma unroll
        for (int j = 0; j < 4; ++j) bfr[j] = *(const short8*)(rb + j * 512);
        #pragma unroll
        for (int i = 0; i < 4; ++i)
            #pragma unroll
            for (int j = 0; j < 4; ++j)
                acc[i][j] = __builtin_amdgcn_mfma_f32_16x16x32_bf16(af[i], bfr[j], acc[i][j], 0, 0, 0);
        __syncthreads();
    }

    const int orow = (lane >> 4) * 4;
    #pragma unroll
    for (int i = 0; i < 4; ++i) {
        const long rbase = m0 + wr * 64 + i * 16 + orow;
        #pragma unroll
        for (int j = 0; j < 4; ++j) {
            const long cidx = n0 + wc * 64 + j * 16 + fr;
            f32x4 v = acc[i][j];
            #pragma unroll
            for (int q = 0; q < 4; ++q) {
                float val = alpha * v[q];
                if constexpr (sizeof(OutT) == 4) C[(rbase + q) * ldc + cidx] = val;
                else                             C[(rbase + q) * ldc + cidx] = f2bf(val);
            }
        }
    }
}

// ---------------------------------------------------------------------------
// f32 [R][Cin] -> bf16 [Cp][R] transposed, zero-filling cols Cin..Cp-1.
// grid (R/32, Cp/32, Z), block 256.
// ---------------------------------------------------------------------------
__global__ __launch_bounds__(256)
void transpose_cast(const float* __restrict__ in, unsigned short* __restrict__ out,
                    int R, int Cin, int Cp, long sin_, long sout_)
{
    __shared__ float t[32][33];
    const int z = blockIdx.z;
    in  += (long)z * sin_;
    out += (long)z * sout_;
    const int r0 = blockIdx.x * 32, c0 = blockIdx.y * 32;
    const int tx = threadIdx.x & 31, ty = threadIdx.x >> 5;
    #pragma unroll
    for (int i = 0; i < 4; ++i) {
        int r = r0 + ty + i * 8, c = c0 + tx;
        t[ty + i * 8][tx] = (c < Cin) ? in[(long)r * Cin + c] : 0.f;
    }
    __syncthreads();
    #pragma unroll
    for (int i = 0; i < 4; ++i) {
        int c = c0 + ty + i * 8, r = r0 + tx;
        if (c < Cp) out[(long)c * R + r] = f2bf(t[tx][ty + i * 8]);
    }
}

// ---------------------------------------------------------------------------
// f32 [R][C] -> bf16 [Rp][C], rows R..Rp-1 zero. 4 elems/thread.
// ---------------------------------------------------------------------------
__global__ __launch_bounds__(256)
void cast_pad(const float* __restrict__ in, unsigned short* __restrict__ out,
              long R, long C, long Rp, long sin_, long sout_, long Z)
{
    long i = (long)blockIdx.x * 256 + threadIdx.x;
    long total = Z * Rp * C / 4;
    if (i >= total) return;
    long e = i * 4;
    long perz = Rp * C;
    long z = e / perz; long rem = e - z * perz;
    long r = rem / C;  long c = rem - r * C;
    ushort4 o = {0, 0, 0, 0};
    if (r < R) {
        const float4 v = *(const float4*)(in + z * sin_ + r * C + c);
        o.x = f2bf(v.x); o.y = f2bf(v.y); o.z = f2bf(v.z); o.w = f2bf(v.w);
    }
    *(ushort4*)(out + z * sout_ + r * C + c) = o;
}

// ---------------------------------------------------------------------------
// InstanceNorm stats over SC [16][512][1024] f32 (pad cols are exact zeros;
// divide by real count 512*960). grid (8 chunks, 16 z), 256 thr.
// ---------------------------------------------------------------------------
__global__ __launch_bounds__(256)
void stats_part(const float* __restrict__ SC, float2* __restrict__ part)
{
    const int z = blockIdx.y, ch = blockIdx.x;
    const float4* p = (const float4*)(SC + (long)z * 524288 + (long)ch * 65536);
    float s = 0.f, s2 = 0.f;
    #pragma unroll 4
    for (int i = 0; i < 64; ++i) {
        float4 v = p[threadIdx.x + i * 256];
        s  += v.x + v.y + v.z + v.w;
        s2 += v.x * v.x + v.y * v.y + v.z * v.z + v.w * v.w;
    }
    __shared__ float sh[256], sh2[256];
    const int tid = threadIdx.x;
    sh[tid] = s; sh2[tid] = s2;
    __syncthreads();
    for (int off = 128; off > 0; off >>= 1) {
        if (tid < off) { sh[tid] += sh[tid + off]; sh2[tid] += sh2[tid + off]; }
        __syncthreads();
    }
    if (tid == 0) part[z * 8 + ch] = make_float2(sh[0], sh2[0]);
}

__global__ void stats_final(const float2* __restrict__ part, float2* __restrict__ stats)
{
    const int t = threadIdx.x;
    if (t < 16) {
        float s = 0.f, s2 = 0.f;
        for (int c = 0; c < 8; ++c) { float2 v = part[t * 8 + c]; s += v.x; s2 += v.y; }
        const float n = 512.f * 960.f;
        float mean = s / n;
        float var = s2 / n - mean * mean;
        // scores are unscaled by sqrt(960): eps_eff = 960 * 1e-5 matches ref exactly
        stats[t] = make_float2(mean, rsqrtf(var + 960.f * 1e-5f));
    }
}

// ---------------------------------------------------------------------------
// normed = (x-mean)*rstd; softmax over 960 real cols; probs bf16 [row][1024],
// pad cols = 0. One block per row (16*512 rows).
// ---------------------------------------------------------------------------
__global__ __launch_bounds__(256)
void norm_softmax(const float* __restrict__ SC, const float2* __restrict__ stats,
                  unsigned short* __restrict__ probs)
{
    const long row = blockIdx.x;
    const int z = (int)(row >> 9);
    const float2 st = stats[z];
    const float* p = SC + row * KVP;
    unsigned short* o = probs + row * KVP;
    const int tid = threadIdx.x;

    float x[4]; float mx = -1e30f;
    #pragma unroll
    for (int r = 0; r < 4; ++r) {
        int j = tid + r * 256;
        x[r] = (j < 960) ? (p[j] - st.x) * st.y : -1e30f;
        mx = fmaxf(mx, x[r]);
    }
    __shared__ float sh[256];
    sh[tid] = mx; __syncthreads();
    for (int off = 128; off > 0; off >>= 1) {
        if (tid < off) sh[tid] = fmaxf(sh[tid], sh[tid + off]);
        __syncthreads();
    }
    mx = sh[0]; __syncthreads();
    float s = 0.f;
    #pragma unroll
    for (int r = 0; r < 4; ++r) {
        int j = tid + r * 256;
        if (j < 960) { x[r] = __expf(x[r] - mx); s += x[r]; }
    }
    sh[tid] = s; __syncthreads();
    for (int off = 128; off > 0; off >>= 1) {
        if (tid < off) sh[tid] += sh[tid + off];
        __syncthreads();
    }
    const float inv = 1.f / sh[0];
    #pragma unroll
    for (int r = 0; r < 4; ++r) {
        int j = tid + r * 256;
        o[j] = (j < 960) ? f2bf(x[r] * inv) : (unsigned short)0;
    }
}

// ---------------------------------------------------------------------------
// UbarT[b] = sum_h UT[b*4+h]  (1/H folded into step-5 alpha). 8 elems/thread.
// ---------------------------------------------------------------------------
__global__ __launch_bounds__(256)
void mean_heads(const unsigned short* __restrict__ UT, unsigned short* __restrict__ Ub)
{
    const long per = KVP * Cz;  // 524288
    long e = ((long)blockIdx.x * 256 + threadIdx.x) * 8;
    long b = e / per; long r = e - b * per;
    const short8 v0 = *(const short8*)(UT + (b * 4 + 0) * per + r);
    const short8 v1 = *(const short8*)(UT + (b * 4 + 1) * per + r);
    const short8 v2 = *(const short8*)(UT + (b * 4 + 2) * per + r);
    const short8 v3 = *(const short8*)(UT + (b * 4 + 3) * per + r);
    short8 o;
    #pragma unroll
    for (int k = 0; k < 8; ++k) {
        float s = bf2f((unsigned short)v0[k]) + bf2f((unsigned short)v1[k])
                + bf2f((unsigned short)v2[k]) + bf2f((unsigned short)v3[k]);
        o[k] = (short)f2bf(s);
    }
    *(short8*)(Ub + b * per + r) = o;
}

// ---------------------------------------------------------------------------
extern "C" void kernel_launch(void* const* d_in, const int* in_sizes, int n_in,
                              void* d_out, int out_size, void* d_ws, size_t ws_size,
                              hipStream_t stream)
{
    const float* emb     = (const float*)d_in[0];  // [4][4096][512]
    const float* emb_all = (const float*)d_in[1];  // [4][4096][960]
    const float* Wq      = (const float*)d_in[2];  // [4][512][512]
    const float* Wk      = (const float*)d_in[3];  // [4][960][960]
    const float* Wv      = (const float*)d_in[4];  // [4][960][960]
    const float* Wo      = (const float*)d_in[5];  // [512][512]
    float* out = (float*)d_out;

    char* ws = (char*)d_ws;
    unsigned short* embT     = (unsigned short*)(ws);              // [b][512][4096]   16.78 MB
    unsigned short* emb_allT = (unsigned short*)(ws + 16777216);   // [b][1024][4096]  33.55 MB
    unsigned short* emb_allB = (unsigned short*)(ws + 50331648);   // [b][4096][960]   31.46 MB
    unsigned short* WqB      = (unsigned short*)(ws + 81788928);   // [h][512][512]     2.10 MB
    unsigned short* WkB      = (unsigned short*)(ws + 83886080);   // [h][1024][960]    7.86 MB
    unsigned short* WvT      = (unsigned short*)(ws + 91750400);   // [h][1024][960]    7.86 MB
    unsigned short* WoB      = (unsigned short*)(ws + 99614720);   // [512][512]        0.52 MB
    unsigned short* GT       = (unsigned short*)(ws + 100139008);  // [b][1024][512]    4.19 MB
    unsigned short* probs    = (unsigned short*)(ws + 104333312);  // [z][512][1024]   16.78 MB
    float2* partials         = (float2*)(ws + 121110528);
    float2* stats            = (float2*)(ws + 121112576);

    // region reuse (sequential liveness)
    unsigned short* S1  = embT;                      // [z][512][1024] bf16
    float*          SCf = (float*)emb_allT;          // [z][512][1024] f32
    unsigned short* UT  = (unsigned short*)emb_allT; // [z][1024][512] bf16
    unsigned short* UbT = GT;                        // [b][1024][512] bf16
    unsigned short* W2  = embT;                      // [b][512][1024] bf16

    // ---- prep casts/transposes ----
    transpose_cast<<<dim3(128, 16, 4), 256, 0, stream>>>(emb,     embT,     4096, 512, 512,  4096L*512, 512L*4096);
    transpose_cast<<<dim3(128, 32, 4), 256, 0, stream>>>(emb_all, emb_allT, 4096, 960, 1024, 4096L*960, 1024L*4096);
    transpose_cast<<<dim3(30,  32, 4), 256, 0, stream>>>(Wv,      WvT,      960,  960, 1024, 960L*960,  1024L*960);
    cast_pad<<<15360, 256, 0, stream>>>(emb_all, emb_allB, 16384, 960, 16384, 0, 0, 1);
    cast_pad<<<1024,  256, 0, stream>>>(Wq,      WqB,      2048,  512, 2048,  0, 0, 1);
    cast_pad<<<3840,  256, 0, stream>>>(Wk,      WkB,      960,   960, 1024,  960L*960, 1024L*960, 4);
    cast_pad<<<256,   256, 0, stream>>>(Wo,      WoB,      512,   512, 512,   0, 0, 1);

    // ---- 1. GT[b] = emb_allT[b] x embT[b]^T  (M=1024, N=512, K=4096) ----
    gemm_bt<unsigned short><<<dim3(4, 8, 4), 256, 0, stream>>>(
        emb_allT, embT, GT, 4096, 4096, 4096, 512,
        1024L*4096, 0, 512L*4096, 0, 1024L*512, 1, 1.f);

    // ---- 2. S1[b,h] = Wq[h] x GT[b]^T  (M=512, N=1024, K=512) ----
    gemm_bt<unsigned short><<<dim3(8, 4, 16), 256, 0, stream>>>(
        WqB, GT, S1, 512, 512, 512, 1024,
        0, 512L*512, 1024L*512, 0, 512L*1024, 4, 1.f);

    // ---- 3. SC[z] = S1[z] x WkB[h]^T  (M=512, N=1024, K=960) ----
    gemm_bt<float><<<dim3(8, 4, 16), 256, 0, stream>>>(
        S1, WkB, SCf, 960, 1024, 960, 1024,
        4L*512*1024, 512L*1024, 0, 1024L*960, 512L*1024, 4, 1.f);

    // ---- 4. InstanceNorm stats + norm/softmax ----
    stats_part<<<dim3(8, 16), 256, 0, stream>>>(SCf, partials);
    stats_final<<<1, 64, 0, stream>>>(partials, stats);
    norm_softmax<<<8192, 256, 0, stream>>>(SCf, stats, probs);

    // ---- 5. UT[z] = WvT[h] x probs[z]^T * 0.25  (M=1024, N=512, K=960) ----
    gemm_bt<unsigned short><<<dim3(4, 8, 16), 256, 0, stream>>>(
        WvT, probs, UT, 960, 960, 1024, 512,
        0, 1024L*960, 4L*512*1024, 512L*1024, 1024L*512, 4, 0.25f);

    // ---- 6. UbT[b] = sum_h UT[b,h] ----
    mean_heads<<<1024, 256, 0, stream>>>(UT, UbT);

    // ---- 7. W2[b] = WoB x UbT[b]^T  (M=512, N=1024, K=512) ----
    gemm_bt<unsigned short><<<dim3(8, 4, 4), 256, 0, stream>>>(
        WoB, UbT, W2, 512, 512, 512, 1024,
        0, 0, 1024L*512, 0, 512L*1024, 1, 1.f);

    // ---- 8. out[b] = emb_allB[b] x W2[b]^T  (M=4096, N=512, K=960) ----
    gemm_bt<float><<<dim3(4, 32, 4), 256, 0, stream>>>(
        emb_allB, W2, out, 960, 960, 1024, 512,
        4096L*960, 0, 512L*1024, 0, 4096L*512, 1, 1.f);
}

// Round 3
// 262.855 us; speedup vs baseline: 9.6255x; 1.1940x over previous
//
#include <hip/hip_runtime.h>
#include <math.h>

typedef __attribute__((ext_vector_type(8))) short short8;
typedef __attribute__((ext_vector_type(4))) float f32x4;

#define Bz 4L
#define Sz 4096L
#define Cz 512L
#define KVz 960L
#define KVP 1024L
#define Hz 4L

__device__ __forceinline__ unsigned short f2bf(float f) {
    unsigned int u; __builtin_memcpy(&u, &f, 4);
    unsigned int r = (u + 0x7FFFu + ((u >> 16) & 1u)) >> 16;
    return (unsigned short)r;
}
__device__ __forceinline__ float bf2f(unsigned short h) {
    unsigned int u = ((unsigned int)h) << 16;
    float f; __builtin_memcpy(&f, &u, 4); return f;
}
__device__ __forceinline__ void gl2lds16(const unsigned short* g, unsigned short* l) {
    __builtin_amdgcn_global_load_lds(
        (const __attribute__((address_space(1))) unsigned int*)g,
        (__attribute__((address_space(3))) unsigned int*)l, 16, 0, 0);
}

// ---------------------------------------------------------------------------
// bf16 MFMA GEMM, m97 structure. C[m][n] = alpha * sum_k A[m,k]*B[n,k].
// Tile 128x128, BK=32, 256 threads = 4 waves (2x2 of 64x64).
// ---------------------------------------------------------------------------
template<typename OutT>
__global__ __launch_bounds__(256)
void gemm_bt(const unsigned short* __restrict__ A, const unsigned short* __restrict__ B,
             OutT* __restrict__ C, int K, long lda, long ldb, long ldc,
             long sa_bb, long sa_bh, long sb_bb, long sb_bh, long sc_z,
             int H, float alpha)
{
    __shared__ unsigned short As[128 * 32];
    __shared__ unsigned short Bs[128 * 32];

    const int z = blockIdx.z;
    const int bb = z / H, hh = z - bb * H;
    A += (long)bb * sa_bb + (long)hh * sa_bh;
    B += (long)bb * sb_bb + (long)hh * sb_bh;
    C += (long)z * sc_z;

    const int tid  = threadIdx.x;
    const int lane = tid & 63;
    const int wave = tid >> 6;
    const int wr = wave >> 1, wc = wave & 1;

    const long m0 = (long)blockIdx.y * 128;
    const long n0 = (long)blockIdx.x * 128;

    const int ch0  = wave * 2;
    const int lrow = lane >> 2;
    const int lcol = (lane & 3) * 8;
    const unsigned short* ga0 = A + (m0 + ch0 * 16 + lrow) * lda + lcol;
    const unsigned short* ga1 = ga0 + 16 * lda;
    const unsigned short* gb0 = B + (n0 + ch0 * 16 + lrow) * ldb + lcol;
    const unsigned short* gb1 = gb0 + 16 * ldb;
    unsigned short* la0 = &As[ch0 * 512];
    unsigned short* la1 = &As[ch0 * 512 + 512];
    unsigned short* lb0 = &Bs[ch0 * 512];
    unsigned short* lb1 = &Bs[ch0 * 512 + 512];

    const int fr = lane & 15;
    const int fk = (lane >> 4) * 8;
    const unsigned short* ra = &As[(wr * 64 + fr) * 32 + fk];
    const unsigned short* rb = &Bs[(wc * 64 + fr) * 32 + fk];

    f32x4 acc[4][4];
    const f32x4 zero4 = {0.f, 0.f, 0.f, 0.f};
    #pragma unroll
    for (int i = 0; i < 4; ++i)
        #pragma unroll
        for (int j = 0; j < 4; ++j) acc[i][j] = zero4;

    for (int k0 = 0; k0 < K; k0 += 32) {
        gl2lds16(ga0, la0); gl2lds16(ga1, la1);
        gl2lds16(gb0, lb0); gl2lds16(gb1, lb1);
        ga0 += 32; ga1 += 32; gb0 += 32; gb1 += 32;
        __syncthreads();

        short8 af[4], bfr[4];
        #pragma unroll
        for (int i = 0; i < 4; ++i) af[i]  = *(const short8*)(ra + i * 512);
        #pragma unroll
        for (int j = 0; j < 4; ++j) bfr[j] = *(const short8*)(rb + j * 512);
        #pragma unroll
        for (int i = 0; i < 4; ++i)
            #pragma unroll
            for (int j = 0; j < 4; ++j)
                acc[i][j] = __builtin_amdgcn_mfma_f32_16x16x32_bf16(af[i], bfr[j], acc[i][j], 0, 0, 0);
        __syncthreads();
    }

    const int orow = (lane >> 4) * 4;
    #pragma unroll
    for (int i = 0; i < 4; ++i) {
        const long rbase = m0 + wr * 64 + i * 16 + orow;
        #pragma unroll
        for (int j = 0; j < 4; ++j) {
            const long cidx = n0 + wc * 64 + j * 16 + fr;
            f32x4 v = acc[i][j];
            #pragma unroll
            for (int q = 0; q < 4; ++q) {
                float val = alpha * v[q];
                if constexpr (sizeof(OutT) == 4) C[(rbase + q) * ldc + cidx] = val;
                else                             C[(rbase + q) * ldc + cidx] = f2bf(val);
            }
        }
    }
}

// ---------------------------------------------------------------------------
// Split-K step 1: part[b][sp][1024][512] f32 = emb_allT[b] x embT[b]^T over
// k-chunk sp. grid (4, 8, 16): z = b*4+sp, K-chunk = 1024, lda=ldb=4096.
// ---------------------------------------------------------------------------
__global__ __launch_bounds__(256)
void gemm_splitk(const unsigned short* __restrict__ A, const unsigned short* __restrict__ B,
                 float* __restrict__ part)
{
    __shared__ unsigned short As[128 * 32];
    __shared__ unsigned short Bs[128 * 32];

    const int z = blockIdx.z;
    const int bb = z >> 2, sp = z & 3;
    A += (long)bb * (1024L * 4096) + (long)sp * 1024;
    B += (long)bb * (512L * 4096) + (long)sp * 1024;
    part += (long)z * (1024L * 512);

    const int tid  = threadIdx.x;
    const int lane = tid & 63;
    const int wave = tid >> 6;
    const int wr = wave >> 1, wc = wave & 1;

    const long m0 = (long)blockIdx.y * 128;
    const long n0 = (long)blockIdx.x * 128;

    const int ch0  = wave * 2;
    const int lrow = lane >> 2;
    const int lcol = (lane & 3) * 8;
    const unsigned short* ga0 = A + (m0 + ch0 * 16 + lrow) * 4096 + lcol;
    const unsigned short* ga1 = ga0 + 16 * 4096;
    const unsigned short* gb0 = B + (n0 + ch0 * 16 + lrow) * 4096 + lcol;
    const unsigned short* gb1 = gb0 + 16 * 4096;
    unsigned short* la0 = &As[ch0 * 512];
    unsigned short* la1 = &As[ch0 * 512 + 512];
    unsigned short* lb0 = &Bs[ch0 * 512];
    unsigned short* lb1 = &Bs[ch0 * 512 + 512];

    const int fr = lane & 15;
    const int fk = (lane >> 4) * 8;
    const unsigned short* ra = &As[(wr * 64 + fr) * 32 + fk];
    const unsigned short* rb = &Bs[(wc * 64 + fr) * 32 + fk];

    f32x4 acc[4][4];
    const f32x4 zero4 = {0.f, 0.f, 0.f, 0.f};
    #pragma unroll
    for (int i = 0; i < 4; ++i)
        #pragma unroll
        for (int j = 0; j < 4; ++j) acc[i][j] = zero4;

    for (int k0 = 0; k0 < 1024; k0 += 32) {
        gl2lds16(ga0, la0); gl2lds16(ga1, la1);
        gl2lds16(gb0, lb0); gl2lds16(gb1, lb1);
        ga0 += 32; ga1 += 32; gb0 += 32; gb1 += 32;
        __syncthreads();

        short8 af[4], bfr[4];
        #pragma unroll
        for (int i = 0; i < 4; ++i) af[i]  = *(const short8*)(ra + i * 512);
        #pragma unroll
        for (int j = 0; j < 4; ++j) bfr[j] = *(const short8*)(rb + j * 512);
        #pragma unroll
        for (int i = 0; i < 4; ++i)
            #pragma unroll
            for (int j = 0; j < 4; ++j)
                acc[i][j] = __builtin_amdgcn_mfma_f32_16x16x32_bf16(af[i], bfr[j], acc[i][j], 0, 0, 0);
        __syncthreads();
    }

    const int orow = (lane >> 4) * 4;
    #pragma unroll
    for (int i = 0; i < 4; ++i) {
        const long rbase = m0 + wr * 64 + i * 16 + orow;
        #pragma unroll
        for (int j = 0; j < 4; ++j) {
            const long cidx = n0 + wc * 64 + j * 16 + fr;
            f32x4 v = acc[i][j];
            #pragma unroll
            for (int q = 0; q < 4; ++q)
                part[(rbase + q) * 512 + cidx] = v[q];
        }
    }
}

// GT[b][r] = f2bf(sum_sp part[b][sp][r]); 4 elems/thread.
__global__ __launch_bounds__(256)
void reduce_gt(const float* __restrict__ part, unsigned short* __restrict__ GT)
{
    long i = ((long)blockIdx.x * 256 + threadIdx.x) * 4;
    long b = i >> 19, r = i & 524287;
    const float* p = part + b * 4 * 524288 + r;
    float4 s0 = *(const float4*)(p);
    float4 s1 = *(const float4*)(p + 524288);
    float4 s2 = *(const float4*)(p + 2 * 524288);
    float4 s3 = *(const float4*)(p + 3 * 524288);
    ushort4 o;
    o.x = f2bf(s0.x + s1.x + s2.x + s3.x);
    o.y = f2bf(s0.y + s1.y + s2.y + s3.y);
    o.z = f2bf(s0.z + s1.z + s2.z + s3.z);
    o.w = f2bf(s0.w + s1.w + s2.w + s3.w);
    *(ushort4*)(GT + i) = o;
}

// ---------------------------------------------------------------------------
// f32 [R][Cin] -> bf16 [Cp][R] transposed, zero-filling cols Cin..Cp-1.
// ---------------------------------------------------------------------------
__global__ __launch_bounds__(256)
void transpose_cast(const float* __restrict__ in, unsigned short* __restrict__ out,
                    int R, int Cin, int Cp, long sin_, long sout_)
{
    __shared__ float t[32][33];
    const int z = blockIdx.z;
    in  += (long)z * sin_;
    out += (long)z * sout_;
    const int r0 = blockIdx.x * 32, c0 = blockIdx.y * 32;
    const int tx = threadIdx.x & 31, ty = threadIdx.x >> 5;
    #pragma unroll
    for (int i = 0; i < 4; ++i) {
        int r = r0 + ty + i * 8, c = c0 + tx;
        t[ty + i * 8][tx] = (c < Cin) ? in[(long)r * Cin + c] : 0.f;
    }
    __syncthreads();
    #pragma unroll
    for (int i = 0; i < 4; ++i) {
        int c = c0 + ty + i * 8, r = r0 + tx;
        if (c < Cp) out[(long)c * R + r] = f2bf(t[tx][ty + i * 8]);
    }
}

// ---------------------------------------------------------------------------
// f32 [R][C] -> bf16 [Rp][C], rows R..Rp-1 zero. 4 elems/thread.
// ---------------------------------------------------------------------------
__global__ __launch_bounds__(256)
void cast_pad(const float* __restrict__ in, unsigned short* __restrict__ out,
              long R, long C, long Rp, long sin_, long sout_, long Z)
{
    long i = (long)blockIdx.x * 256 + threadIdx.x;
    long total = Z * Rp * C / 4;
    if (i >= total) return;
    long e = i * 4;
    long perz = Rp * C;
    long z = e / perz; long rem = e - z * perz;
    long r = rem / C;  long c = rem - r * C;
    ushort4 o = {0, 0, 0, 0};
    if (r < R) {
        const float4 v = *(const float4*)(in + z * sin_ + r * C + c);
        o.x = f2bf(v.x); o.y = f2bf(v.y); o.z = f2bf(v.z); o.w = f2bf(v.w);
    }
    *(ushort4*)(out + z * sout_ + r * C + c) = o;
}

// ---------------------------------------------------------------------------
// InstanceNorm stats over SC [16][512][1024] f32.
// ---------------------------------------------------------------------------
__global__ __launch_bounds__(256)
void stats_part(const float* __restrict__ SC, float2* __restrict__ part)
{
    const int z = blockIdx.y, ch = blockIdx.x;
    const float4* p = (const float4*)(SC + (long)z * 524288 + (long)ch * 65536);
    float s = 0.f, s2 = 0.f;
    #pragma unroll 4
    for (int i = 0; i < 64; ++i) {
        float4 v = p[threadIdx.x + i * 256];
        s  += v.x + v.y + v.z + v.w;
        s2 += v.x * v.x + v.y * v.y + v.z * v.z + v.w * v.w;
    }
    __shared__ float sh[256], sh2[256];
    const int tid = threadIdx.x;
    sh[tid] = s; sh2[tid] = s2;
    __syncthreads();
    for (int off = 128; off > 0; off >>= 1) {
        if (tid < off) { sh[tid] += sh[tid + off]; sh2[tid] += sh2[tid + off]; }
        __syncthreads();
    }
    if (tid == 0) part[z * 8 + ch] = make_float2(sh[0], sh2[0]);
}

__global__ void stats_final(const float2* __restrict__ part, float2* __restrict__ stats)
{
    const int t = threadIdx.x;
    if (t < 16) {
        float s = 0.f, s2 = 0.f;
        for (int c = 0; c < 8; ++c) { float2 v = part[t * 8 + c]; s += v.x; s2 += v.y; }
        const float n = 512.f * 960.f;
        float mean = s / n;
        float var = s2 / n - mean * mean;
        stats[t] = make_float2(mean, rsqrtf(var + 960.f * 1e-5f));
    }
}

// ---------------------------------------------------------------------------
// norm + softmax over 960 real cols; probs bf16 [row][1024], pad cols = 0.
// ---------------------------------------------------------------------------
__global__ __launch_bounds__(256)
void norm_softmax(const float* __restrict__ SC, const float2* __restrict__ stats,
                  unsigned short* __restrict__ probs)
{
    const long row = blockIdx.x;
    const int z = (int)(row >> 9);
    const float2 st = stats[z];
    const float* p = SC + row * KVP;
    unsigned short* o = probs + row * KVP;
    const int tid = threadIdx.x;

    float x[4]; float mx = -1e30f;
    #pragma unroll
    for (int r = 0; r < 4; ++r) {
        int j = tid + r * 256;
        x[r] = (j < 960) ? (p[j] - st.x) * st.y : -1e30f;
        mx = fmaxf(mx, x[r]);
    }
    __shared__ float sh[256];
    sh[tid] = mx; __syncthreads();
    for (int off = 128; off > 0; off >>= 1) {
        if (tid < off) sh[tid] = fmaxf(sh[tid], sh[tid + off]);
        __syncthreads();
    }
    mx = sh[0]; __syncthreads();
    float s = 0.f;
    #pragma unroll
    for (int r = 0; r < 4; ++r) {
        int j = tid + r * 256;
        if (j < 960) { x[r] = __expf(x[r] - mx); s += x[r]; }
    }
    sh[tid] = s; __syncthreads();
    for (int off = 128; off > 0; off >>= 1) {
        if (tid < off) sh[tid] += sh[tid + off];
        __syncthreads();
    }
    const float inv = 1.f / sh[0];
    #pragma unroll
    for (int r = 0; r < 4; ++r) {
        int j = tid + r * 256;
        o[j] = (j < 960) ? f2bf(x[r] * inv) : (unsigned short)0;
    }
}

// ---------------------------------------------------------------------------
// UbarT[b] = sum_h UT[b*4+h]; 8 elems/thread.
// ---------------------------------------------------------------------------
__global__ __launch_bounds__(256)
void mean_heads(const unsigned short* __restrict__ UT, unsigned short* __restrict__ Ub)
{
    const long per = KVP * Cz;
    long e = ((long)blockIdx.x * 256 + threadIdx.x) * 8;
    long b = e / per; long r = e - b * per;
    const short8 v0 = *(const short8*)(UT + (b * 4 + 0) * per + r);
    const short8 v1 = *(const short8*)(UT + (b * 4 + 1) * per + r);
    const short8 v2 = *(const short8*)(UT + (b * 4 + 2) * per + r);
    const short8 v3 = *(const short8*)(UT + (b * 4 + 3) * per + r);
    short8 o;
    #pragma unroll
    for (int k = 0; k < 8; ++k) {
        float s = bf2f((unsigned short)v0[k]) + bf2f((unsigned short)v1[k])
                + bf2f((unsigned short)v2[k]) + bf2f((unsigned short)v3[k]);
        o[k] = (short)f2bf(s);
    }
    *(short8*)(Ub + b * per + r) = o;
}

// ---------------------------------------------------------------------------
extern "C" void kernel_launch(void* const* d_in, const int* in_sizes, int n_in,
                              void* d_out, int out_size, void* d_ws, size_t ws_size,
                              hipStream_t stream)
{
    const float* emb     = (const float*)d_in[0];  // [4][4096][512]
    const float* emb_all = (const float*)d_in[1];  // [4][4096][960]
    const float* Wq      = (const float*)d_in[2];  // [4][512][512]
    const float* Wk      = (const float*)d_in[3];  // [4][960][960]
    const float* Wv      = (const float*)d_in[4];  // [4][960][960]
    const float* Wo      = (const float*)d_in[5];  // [512][512]
    float* out = (float*)d_out;

    char* ws = (char*)d_ws;
    unsigned short* embT     = (unsigned short*)(ws);              // [b][512][4096]
    unsigned short* emb_allT = (unsigned short*)(ws + 16777216);   // [b][1024][4096]
    unsigned short* emb_allB = (unsigned short*)(ws + 50331648);   // [b][4096][960]
    unsigned short* WqB      = (unsigned short*)(ws + 81788928);   // [h][512][512]
    unsigned short* WkB      = (unsigned short*)(ws + 83886080);   // [h][1024][960]
    unsigned short* WvT      = (unsigned short*)(ws + 91750400);   // [h][1024][960]
    unsigned short* WoB      = (unsigned short*)(ws + 99614720);   // [512][512]
    unsigned short* GT       = (unsigned short*)(ws + 100139008);  // [b][1024][512]
    unsigned short* probs    = (unsigned short*)(ws + 104333312);  // [z][512][1024]
    float2* partials         = (float2*)(ws + 121110528);
    float2* stats            = (float2*)(ws + 121112576);

    // split-K partials: 4*4*524288 f32 = 32 MB, overlays emb_allB+WqB
    // (both dead until after reduce_gt; their casts run after it)
    float* partK = (float*)(ws + 50331648);

    // region reuse (sequential liveness)
    unsigned short* S1  = embT;
    float*          SCf = (float*)emb_allT;
    unsigned short* UT  = (unsigned short*)emb_allT;
    unsigned short* UbT = GT;
    unsigned short* W2  = embT;

    // ---- preps needed for step 1 (+ weight preps outside partK region) ----
    transpose_cast<<<dim3(128, 16, 4), 256, 0, stream>>>(emb,     embT,     4096, 512, 512,  4096L*512, 512L*4096);
    transpose_cast<<<dim3(128, 32, 4), 256, 0, stream>>>(emb_all, emb_allT, 4096, 960, 1024, 4096L*960, 1024L*4096);
    transpose_cast<<<dim3(30,  32, 4), 256, 0, stream>>>(Wv,      WvT,      960,  960, 1024, 960L*960,  1024L*960);
    cast_pad<<<3840, 256, 0, stream>>>(Wk, WkB, 960, 960, 1024, 960L*960, 1024L*960, 4);
    cast_pad<<<256,  256, 0, stream>>>(Wo, WoB, 512, 512, 512,  0, 0, 1);

    // ---- 1. split-K: part[b,sp] = emb_allT x embT^T chunks, then reduce ----
    gemm_splitk<<<dim3(4, 8, 16), 256, 0, stream>>>(emb_allT, embT, partK);
    reduce_gt<<<2048, 256, 0, stream>>>(partK, GT);

    // ---- deferred preps (overlapped partK region now dead) ----
    cast_pad<<<15360, 256, 0, stream>>>(emb_all, emb_allB, 16384, 960, 16384, 0, 0, 1);
    cast_pad<<<1024,  256, 0, stream>>>(Wq,      WqB,      2048,  512, 2048,  0, 0, 1);

    // ---- 2. S1[b,h] = Wq[h] x GT[b]^T  (M=512, N=1024, K=512) ----
    gemm_bt<unsigned short><<<dim3(8, 4, 16), 256, 0, stream>>>(
        WqB, GT, S1, 512, 512, 512, 1024,
        0, 512L*512, 1024L*512, 0, 512L*1024, 4, 1.f);

    // ---- 3. SC[z] = S1[z] x WkB[h]^T  (M=512, N=1024, K=960) ----
    gemm_bt<float><<<dim3(8, 4, 16), 256, 0, stream>>>(
        S1, WkB, SCf, 960, 1024, 960, 1024,
        4L*512*1024, 512L*1024, 0, 1024L*960, 512L*1024, 4, 1.f);

    // ---- 4. InstanceNorm stats + norm/softmax ----
    stats_part<<<dim3(8, 16), 256, 0, stream>>>(SCf, partials);
    stats_final<<<1, 64, 0, stream>>>(partials, stats);
    norm_softmax<<<8192, 256, 0, stream>>>(SCf, stats, probs);

    // ---- 5. UT[z] = WvT[h] x probs[z]^T * 0.25  (M=1024, N=512, K=960) ----
    gemm_bt<unsigned short><<<dim3(4, 8, 16), 256, 0, stream>>>(
        WvT, probs, UT, 960, 960, 1024, 512,
        0, 1024L*960, 4L*512*1024, 512L*1024, 1024L*512, 4, 0.25f);

    // ---- 6. UbT[b] = sum_h UT[b,h] ----
    mean_heads<<<1024, 256, 0, stream>>>(UT, UbT);

    // ---- 7. W2[b] = WoB x UbT[b]^T  (M=512, N=1024, K=512) ----
    gemm_bt<unsigned short><<<dim3(8, 4, 4), 256, 0, stream>>>(
        WoB, UbT, W2, 512, 512, 512, 1024,
        0, 0, 1024L*512, 0, 512L*1024, 1, 1.f);

    // ---- 8. out[b] = emb_allB[b] x W2[b]^T  (M=4096, N=512, K=960) ----
    gemm_bt<float><<<dim3(4, 32, 4), 256, 0, stream>>>(
        emb_allB, W2, out, 960, 960, 1024, 512,
        4096L*960, 0, 512L*1024, 0, 4096L*512, 1, 1.f);
}

// Round 4
// 249.385 us; speedup vs baseline: 10.1454x; 1.0540x over previous
//
#include <hip/hip_runtime.h>
#include <math.h>

typedef __attribute__((ext_vector_type(8))) short short8;
typedef __attribute__((ext_vector_type(4))) float f32x4;

#define Bz 4L
#define Sz 4096L
#define Cz 512L
#define KVz 960L
#define KVP 1024L
#define Hz 4L

__device__ __forceinline__ unsigned short f2bf(float f) {
    unsigned int u; __builtin_memcpy(&u, &f, 4);
    unsigned int r = (u + 0x7FFFu + ((u >> 16) & 1u)) >> 16;
    return (unsigned short)r;
}
__device__ __forceinline__ float bf2f(unsigned short h) {
    unsigned int u = ((unsigned int)h) << 16;
    float f; __builtin_memcpy(&f, &u, 4); return f;
}
__device__ __forceinline__ void gl2lds16(const unsigned short* g, unsigned short* l) {
    __builtin_amdgcn_global_load_lds(
        (const __attribute__((address_space(1))) unsigned int*)g,
        (__attribute__((address_space(3))) unsigned int*)l, 16, 0, 0);
}

// ---------------------------------------------------------------------------
// bf16 MFMA GEMM, double-buffered 2-phase pipeline (T3 minimum recipe):
//   prologue: STAGE(buf0); barrier;
//   loop:     STAGE(buf^1, next) ; ds_read(buf)+MFMA ; barrier ; swap
// The single barrier's vmcnt(0) drain lands AFTER the current tile's compute,
// so stage latency overlaps MFMA instead of being serially exposed.
// C[m][n] = alpha * sum_k A[m,k]*B[n,k]; tile 128x128, BK=32, 4 waves.
// STATS: also emit per-block (sum, sumsq) partials for InstanceNorm.
// ---------------------------------------------------------------------------
template<typename OutT, bool STATS>
__global__ __launch_bounds__(256)
void gemm_bt(const unsigned short* __restrict__ A, const unsigned short* __restrict__ B,
             OutT* __restrict__ C, float2* __restrict__ sp_out,
             int K, long lda, long ldb, long ldc,
             long sa_bb, long sa_bh, long sb_bb, long sb_bh, long sc_z,
             int H, float alpha)
{
    __shared__ unsigned short As[2][128 * 32];
    __shared__ unsigned short Bs[2][128 * 32];

    const int z = blockIdx.z;
    const int bb = z / H, hh = z - bb * H;
    A += (long)bb * sa_bb + (long)hh * sa_bh;
    B += (long)bb * sb_bb + (long)hh * sb_bh;
    C += (long)z * sc_z;

    const int tid  = threadIdx.x;
    const int lane = tid & 63;
    const int wave = tid >> 6;
    const int wr = wave >> 1, wc = wave & 1;

    const long m0 = (long)blockIdx.y * 128;
    const long n0 = (long)blockIdx.x * 128;

    // staging: wave w covers chunks (2w, 2w+1); chunk = 16 rows x 32 k (1 KiB)
    const int ch0  = wave * 2;
    const int lrow = lane >> 2;
    const int lcol = (lane & 3) * 8;
    const unsigned short* ga0 = A + (m0 + ch0 * 16 + lrow) * lda + lcol;
    const unsigned short* ga1 = ga0 + 16 * lda;
    const unsigned short* gb0 = B + (n0 + ch0 * 16 + lrow) * ldb + lcol;
    const unsigned short* gb1 = gb0 + 16 * ldb;

    auto stg = [&](int buf, long koff) {
        gl2lds16(ga0 + koff, &As[buf][ch0 * 512]);
        gl2lds16(ga1 + koff, &As[buf][ch0 * 512 + 512]);
        gl2lds16(gb0 + koff, &Bs[buf][ch0 * 512]);
        gl2lds16(gb1 + koff, &Bs[buf][ch0 * 512 + 512]);
    };

    const int fr = lane & 15;
    const int fk = (lane >> 4) * 8;

    f32x4 acc[4][4];
    const f32x4 zero4 = {0.f, 0.f, 0.f, 0.f};
    #pragma unroll
    for (int i = 0; i < 4; ++i)
        #pragma unroll
        for (int j = 0; j < 4; ++j) acc[i][j] = zero4;

    stg(0, 0);
    __syncthreads();

    int cur = 0;
    for (long k0 = 0; k0 < K; k0 += 32) {
        if (k0 + 32 < K) stg(cur ^ 1, k0 + 32);

        const unsigned short* ra = &As[cur][(wr * 64 + fr) * 32 + fk];
        const unsigned short* rb = &Bs[cur][(wc * 64 + fr) * 32 + fk];
        short8 af[4], bfr[4];
        #pragma unroll
        for (int i = 0; i < 4; ++i) af[i]  = *(const short8*)(ra + i * 512);
        #pragma unroll
        for (int j = 0; j < 4; ++j) bfr[j] = *(const short8*)(rb + j * 512);
        #pragma unroll
        for (int i = 0; i < 4; ++i)
            #pragma unroll
            for (int j = 0; j < 4; ++j)
                acc[i][j] = __builtin_amdgcn_mfma_f32_16x16x32_bf16(af[i], bfr[j], acc[i][j], 0, 0, 0);

        __syncthreads();   // drains vmcnt (next tile landed) + protects buf reuse
        cur ^= 1;
    }

    float s = 0.f, s2 = 0.f;
    const int orow = (lane >> 4) * 4;
    #pragma unroll
    for (int i = 0; i < 4; ++i) {
        const long rbase = m0 + wr * 64 + i * 16 + orow;
        #pragma unroll
        for (int j = 0; j < 4; ++j) {
            const long cidx = n0 + wc * 64 + j * 16 + fr;
            f32x4 v = acc[i][j];
            #pragma unroll
            for (int q = 0; q < 4; ++q) {
                float val = alpha * v[q];
                if constexpr (STATS) { s += val; s2 += val * val; }
                if constexpr (sizeof(OutT) == 4) C[(rbase + q) * ldc + cidx] = val;
                else                             C[(rbase + q) * ldc + cidx] = f2bf(val);
            }
        }
    }

    if constexpr (STATS) {
        float* red = (float*)&As[0][0];   // LDS free after final loop barrier
        red[tid] = s; red[256 + tid] = s2;
        __syncthreads();
        for (int off = 128; off > 0; off >>= 1) {
            if (tid < off) { red[tid] += red[tid + off]; red[256 + tid] += red[256 + tid + off]; }
            __syncthreads();
        }
        if (tid == 0)
            sp_out[(long)z * 32 + blockIdx.y * gridDim.x + blockIdx.x] =
                make_float2(red[0], red[256]);
    }
}

// ---------------------------------------------------------------------------
// f32 [R][Cin] -> bf16 [Cp][R] transposed, zero-filling cols Cin..Cp-1.
// ---------------------------------------------------------------------------
__global__ __launch_bounds__(256)
void transpose_cast(const float* __restrict__ in, unsigned short* __restrict__ out,
                    int R, int Cin, int Cp, long sin_, long sout_)
{
    __shared__ float t[32][33];
    const int z = blockIdx.z;
    in  += (long)z * sin_;
    out += (long)z * sout_;
    const int r0 = blockIdx.x * 32, c0 = blockIdx.y * 32;
    const int tx = threadIdx.x & 31, ty = threadIdx.x >> 5;
    #pragma unroll
    for (int i = 0; i < 4; ++i) {
        int r = r0 + ty + i * 8, c = c0 + tx;
        t[ty + i * 8][tx] = (c < Cin) ? in[(long)r * Cin + c] : 0.f;
    }
    __syncthreads();
    #pragma unroll
    for (int i = 0; i < 4; ++i) {
        int c = c0 + ty + i * 8, r = r0 + tx;
        if (c < Cp) out[(long)c * R + r] = f2bf(t[tx][ty + i * 8]);
    }
}

// ---------------------------------------------------------------------------
// All three weight casts in one launch (quad-vectorized):
//  seg0: Wk [4][960][960] -> WkB [4][1024][960] (pad rows zero)
//  seg1: Wq [4][512][512] -> WqB (straight cast)
//  seg2: Wo [512][512]    -> WoB (straight cast)
// ---------------------------------------------------------------------------
__global__ __launch_bounds__(256)
void prep_weights(const float* __restrict__ Wk, const float* __restrict__ Wq,
                  const float* __restrict__ Wo,
                  unsigned short* __restrict__ WkB, unsigned short* __restrict__ WqB,
                  unsigned short* __restrict__ WoB)
{
    long q = (long)blockIdx.x * 256 + threadIdx.x;
    if (q < 983040) {                     // WkB: 4*1024*960/4 quads
        long e = q * 4;
        long h = e / 983040L; long r2 = e - h * 983040L;
        long r = r2 / 960;    long c = r2 - r * 960;
        ushort4 o = {0, 0, 0, 0};
        if (r < 960) {
            float4 v = *(const float4*)(Wk + (h * 960 + r) * 960 + c);
            o.x = f2bf(v.x); o.y = f2bf(v.y); o.z = f2bf(v.z); o.w = f2bf(v.w);
        }
        *(ushort4*)(WkB + e) = o;
        return;
    }
    q -= 983040;
    if (q < 262144) {                     // WqB: 4*512*512/4 quads
        long e = q * 4;
        float4 v = *(const float4*)(Wq + e);
        ushort4 o; o.x = f2bf(v.x); o.y = f2bf(v.y); o.z = f2bf(v.z); o.w = f2bf(v.w);
        *(ushort4*)(WqB + e) = o;
        return;
    }
    q -= 262144;
    if (q < 65536) {                      // WoB: 512*512/4 quads
        long e = q * 4;
        float4 v = *(const float4*)(Wo + e);
        ushort4 o; o.x = f2bf(v.x); o.y = f2bf(v.y); o.z = f2bf(v.z); o.w = f2bf(v.w);
        *(ushort4*)(WoB + e) = o;
    }
}

// ---------------------------------------------------------------------------
// f32 [R][C] -> bf16 [Rp][C], rows R..Rp-1 zero. 4 elems/thread.
// ---------------------------------------------------------------------------
__global__ __launch_bounds__(256)
void cast_pad(const float* __restrict__ in, unsigned short* __restrict__ out,
              long R, long C, long Rp, long sin_, long sout_, long Z)
{
    long i = (long)blockIdx.x * 256 + threadIdx.x;
    long total = Z * Rp * C / 4;
    if (i >= total) return;
    long e = i * 4;
    long perz = Rp * C;
    long z = e / perz; long rem = e - z * perz;
    long r = rem / C;  long c = rem - r * C;
    ushort4 o = {0, 0, 0, 0};
    if (r < R) {
        const float4 v = *(const float4*)(in + z * sin_ + r * C + c);
        o.x = f2bf(v.x); o.y = f2bf(v.y); o.z = f2bf(v.z); o.w = f2bf(v.w);
    }
    *(ushort4*)(out + z * sout_ + r * C + c) = o;
}

// GT[b][r] = f2bf(sum_sp part[b][sp][r]); 4 elems/thread.
__global__ __launch_bounds__(256)
void reduce_gt(const float* __restrict__ part, unsigned short* __restrict__ GT)
{
    long i = ((long)blockIdx.x * 256 + threadIdx.x) * 4;
    long b = i >> 19, r = i & 524287;
    const float* p = part + b * 4 * 524288 + r;
    float4 s0 = *(const float4*)(p);
    float4 s1 = *(const float4*)(p + 524288);
    float4 s2 = *(const float4*)(p + 2 * 524288);
    float4 s3 = *(const float4*)(p + 3 * 524288);
    ushort4 o;
    o.x = f2bf(s0.x + s1.x + s2.x + s3.x);
    o.y = f2bf(s0.y + s1.y + s2.y + s3.y);
    o.z = f2bf(s0.z + s1.z + s2.z + s3.z);
    o.w = f2bf(s0.w + s1.w + s2.w + s3.w);
    *(ushort4*)(GT + i) = o;
}

// ---------------------------------------------------------------------------
// norm + softmax; mean/rstd reduced from the 32 per-block GEMM partials.
// probs bf16 [row][1024], pad cols = 0. One block per row.
// ---------------------------------------------------------------------------
__global__ __launch_bounds__(256)
void norm_softmax(const float* __restrict__ SC, const float2* __restrict__ part,
                  unsigned short* __restrict__ probs)
{
    const long row = blockIdx.x;
    const int z = (int)(row >> 9);
    float s0 = 0.f, s20 = 0.f;
    #pragma unroll
    for (int i = 0; i < 32; ++i) {
        float2 v = part[z * 32 + i];
        s0 += v.x; s20 += v.y;
    }
    const float ninv = 1.f / (512.f * 960.f);
    const float mean = s0 * ninv;
    const float rstd = rsqrtf(s20 * ninv - mean * mean + 960.f * 1e-5f);

    const float* p = SC + row * KVP;
    unsigned short* o = probs + row * KVP;
    const int tid = threadIdx.x;

    float x[4]; float mx = -1e30f;
    #pragma unroll
    for (int r = 0; r < 4; ++r) {
        int j = tid + r * 256;
        x[r] = (j < 960) ? (p[j] - mean) * rstd : -1e30f;
        mx = fmaxf(mx, x[r]);
    }
    __shared__ float sh[256];
    sh[tid] = mx; __syncthreads();
    for (int off = 128; off > 0; off >>= 1) {
        if (tid < off) sh[tid] = fmaxf(sh[tid], sh[tid + off]);
        __syncthreads();
    }
    mx = sh[0]; __syncthreads();
    float s = 0.f;
    #pragma unroll
    for (int r = 0; r < 4; ++r) {
        int j = tid + r * 256;
        if (j < 960) { x[r] = __expf(x[r] - mx); s += x[r]; }
    }
    sh[tid] = s; __syncthreads();
    for (int off = 128; off > 0; off >>= 1) {
        if (tid < off) sh[tid] += sh[tid + off];
        __syncthreads();
    }
    const float inv = 1.f / sh[0];
    #pragma unroll
    for (int r = 0; r < 4; ++r) {
        int j = tid + r * 256;
        o[j] = (j < 960) ? f2bf(x[r] * inv) : (unsigned short)0;
    }
}

// ---------------------------------------------------------------------------
// UbarT[b] = sum_h UT[b*4+h]; 8 elems/thread.
// ---------------------------------------------------------------------------
__global__ __launch_bounds__(256)
void mean_heads(const unsigned short* __restrict__ UT, unsigned short* __restrict__ Ub)
{
    const long per = KVP * Cz;
    long e = ((long)blockIdx.x * 256 + threadIdx.x) * 8;
    long b = e / per; long r = e - b * per;
    const short8 v0 = *(const short8*)(UT + (b * 4 + 0) * per + r);
    const short8 v1 = *(const short8*)(UT + (b * 4 + 1) * per + r);
    const short8 v2 = *(const short8*)(UT + (b * 4 + 2) * per + r);
    const short8 v3 = *(const short8*)(UT + (b * 4 + 3) * per + r);
    short8 o;
    #pragma unroll
    for (int k = 0; k < 8; ++k) {
        float s = bf2f((unsigned short)v0[k]) + bf2f((unsigned short)v1[k])
                + bf2f((unsigned short)v2[k]) + bf2f((unsigned short)v3[k]);
        o[k] = (short)f2bf(s);
    }
    *(short8*)(Ub + b * per + r) = o;
}

// ---------------------------------------------------------------------------
extern "C" void kernel_launch(void* const* d_in, const int* in_sizes, int n_in,
                              void* d_out, int out_size, void* d_ws, size_t ws_size,
                              hipStream_t stream)
{
    const float* emb     = (const float*)d_in[0];  // [4][4096][512]
    const float* emb_all = (const float*)d_in[1];  // [4][4096][960]
    const float* Wq      = (const float*)d_in[2];  // [4][512][512]
    const float* Wk      = (const float*)d_in[3];  // [4][960][960]
    const float* Wv      = (const float*)d_in[4];  // [4][960][960]
    const float* Wo      = (const float*)d_in[5];  // [512][512]
    float* out = (float*)d_out;

    char* ws = (char*)d_ws;
    unsigned short* embT     = (unsigned short*)(ws);              // [b][512][4096]
    unsigned short* emb_allT = (unsigned short*)(ws + 16777216);   // [b][1024][4096]
    unsigned short* emb_allB = (unsigned short*)(ws + 50331648);   // [b][4096][960]
    unsigned short* WqB      = (unsigned short*)(ws + 81788928);   // [h][512][512]
    unsigned short* WkB      = (unsigned short*)(ws + 83886080);   // [h][1024][960]
    unsigned short* WvT      = (unsigned short*)(ws + 91750400);   // [h][1024][960]
    unsigned short* WoB      = (unsigned short*)(ws + 99614720);   // [512][512]
    unsigned short* GT       = (unsigned short*)(ws + 100139008);  // [b][1024][512]
    unsigned short* probs    = (unsigned short*)(ws + 104333312);  // [z][512][1024]
    float2* sc_part          = (float2*)(ws + 121110528);          // [16][32]
    float*  partK            = (float*)(ws + 134217728);           // 32 MB, own region

    // region reuse (sequential liveness)
    unsigned short* S1  = embT;                      // dead: embT after step 1
    float*          SCf = (float*)emb_allT;         // dead: emb_allT after step 1
    unsigned short* UT  = (unsigned short*)emb_allT; // dead: SCf after softmax
    unsigned short* UbT = GT;                        // dead: GT after step 2
    unsigned short* W2  = embT;                      // dead: S1 after step 3

    // ---- all preps upfront ----
    prep_weights<<<5120, 256, 0, stream>>>(Wk, Wq, Wo, WkB, WqB, WoB);
    transpose_cast<<<dim3(128, 16, 4), 256, 0, stream>>>(emb,     embT,     4096, 512, 512,  4096L*512, 512L*4096);
    transpose_cast<<<dim3(128, 32, 4), 256, 0, stream>>>(emb_all, emb_allT, 4096, 960, 1024, 4096L*960, 1024L*4096);
    transpose_cast<<<dim3(30,  32, 4), 256, 0, stream>>>(Wv,      WvT,      960,  960, 1024, 960L*960,  1024L*960);
    cast_pad<<<15360, 256, 0, stream>>>(emb_all, emb_allB, 16384, 960, 16384, 0, 0, 1);

    // ---- 1. split-K (z = b*4+sp): partK[z] = emb_allT chunk x embT chunk^T ----
    gemm_bt<float, false><<<dim3(4, 8, 16), 256, 0, stream>>>(
        emb_allT, embT, partK, nullptr, 1024, 4096, 4096, 512,
        1024L*4096, 1024, 512L*4096, 1024, 1024L*512, 4, 1.f);
    reduce_gt<<<2048, 256, 0, stream>>>(partK, GT);

    // ---- 2. S1[b,h] = Wq[h] x GT[b]^T  (M=512, N=1024, K=512) ----
    gemm_bt<unsigned short, false><<<dim3(8, 4, 16), 256, 0, stream>>>(
        WqB, GT, S1, nullptr, 512, 512, 512, 1024,
        0, 512L*512, 1024L*512, 0, 512L*1024, 4, 1.f);

    // ---- 3. SC[z] = S1[z] x WkB[h]^T  + fused stats partials ----
    gemm_bt<float, true><<<dim3(8, 4, 16), 256, 0, stream>>>(
        S1, WkB, SCf, sc_part, 960, 1024, 960, 1024,
        4L*512*1024, 512L*1024, 0, 1024L*960, 512L*1024, 4, 1.f);

    // ---- 4. fused instance-norm + softmax ----
    norm_softmax<<<8192, 256, 0, stream>>>(SCf, sc_part, probs);

    // ---- 5. UT[z] = WvT[h] x probs[z]^T * 0.25  (M=1024, N=512, K=960) ----
    gemm_bt<unsigned short, false><<<dim3(4, 8, 16), 256, 0, stream>>>(
        WvT, probs, UT, nullptr, 960, 960, 1024, 512,
        0, 1024L*960, 4L*512*1024, 512L*1024, 1024L*512, 4, 0.25f);

    // ---- 6. UbT[b] = sum_h UT[b,h] ----
    mean_heads<<<1024, 256, 0, stream>>>(UT, UbT);

    // ---- 7. W2[b] = WoB x UbT[b]^T  (M=512, N=1024, K=512) ----
    gemm_bt<unsigned short, false><<<dim3(8, 4, 4), 256, 0, stream>>>(
        WoB, UbT, W2, nullptr, 512, 512, 512, 1024,
        0, 0, 1024L*512, 0, 512L*1024, 1, 1.f);

    // ---- 8. out[b] = emb_allB[b] x W2[b]^T  (M=4096, N=512, K=960) ----
    gemm_bt<float, false><<<dim3(4, 32, 4), 256, 0, stream>>>(
        emb_allB, W2, out, nullptr, 960, 960, 1024, 512,
        4096L*960, 0, 512L*1024, 0, 4096L*512, 1, 1.f);
}

// Round 5
// 240.926 us; speedup vs baseline: 10.5016x; 1.0351x over previous
//
#include <hip/hip_runtime.h>
#include <math.h>

typedef __attribute__((ext_vector_type(8))) short short8;
typedef __attribute__((ext_vector_type(4))) float f32x4;

__device__ __forceinline__ unsigned short f2bf(float f) {
    unsigned int u; __builtin_memcpy(&u, &f, 4);
    unsigned int r = (u + 0x7FFFu + ((u >> 16) & 1u)) >> 16;
    return (unsigned short)r;
}
__device__ __forceinline__ float bf2f(unsigned short h) {
    unsigned int u = ((unsigned int)h) << 16;
    float f; __builtin_memcpy(&f, &u, 4); return f;
}
__device__ __forceinline__ void gl2lds16(const unsigned short* g, unsigned short* l) {
    __builtin_amdgcn_global_load_lds(
        (const __attribute__((address_space(1))) unsigned int*)g,
        (__attribute__((address_space(3))) unsigned int*)l, 16, 0, 0);
}

// ---------------------------------------------------------------------------
// bf16 MFMA GEMM, double-buffered 2-phase pipeline.
// C[m][n] = alpha * sum_k A[m,k]*B[n,k]; tile 128x128, BK=32, 4 waves.
// STATS: also emit per-block (sum, sumsq) fp32 partials for InstanceNorm.
// ---------------------------------------------------------------------------
template<typename OutT, bool STATS>
__global__ __launch_bounds__(256)
void gemm_bt(const unsigned short* __restrict__ A, const unsigned short* __restrict__ B,
             OutT* __restrict__ C, float2* __restrict__ sp_out,
             int K, long lda, long ldb, long ldc,
             long sa_bb, long sa_bh, long sb_bb, long sb_bh, long sc_z,
             int H, float alpha)
{
    __shared__ unsigned short As[2][128 * 32];
    __shared__ unsigned short Bs[2][128 * 32];

    const int z = blockIdx.z;
    const int bb = z / H, hh = z - bb * H;
    A += (long)bb * sa_bb + (long)hh * sa_bh;
    B += (long)bb * sb_bb + (long)hh * sb_bh;
    C += (long)z * sc_z;

    const int tid  = threadIdx.x;
    const int lane = tid & 63;
    const int wave = tid >> 6;
    const int wr = wave >> 1, wc = wave & 1;

    const long m0 = (long)blockIdx.y * 128;
    const long n0 = (long)blockIdx.x * 128;

    const int ch0  = wave * 2;
    const int lrow = lane >> 2;
    const int lcol = (lane & 3) * 8;
    const unsigned short* ga0 = A + (m0 + ch0 * 16 + lrow) * lda + lcol;
    const unsigned short* ga1 = ga0 + 16 * lda;
    const unsigned short* gb0 = B + (n0 + ch0 * 16 + lrow) * ldb + lcol;
    const unsigned short* gb1 = gb0 + 16 * ldb;

    auto stg = [&](int buf, long koff) {
        gl2lds16(ga0 + koff, &As[buf][ch0 * 512]);
        gl2lds16(ga1 + koff, &As[buf][ch0 * 512 + 512]);
        gl2lds16(gb0 + koff, &Bs[buf][ch0 * 512]);
        gl2lds16(gb1 + koff, &Bs[buf][ch0 * 512 + 512]);
    };

    const int fr = lane & 15;
    const int fk = (lane >> 4) * 8;

    f32x4 acc[4][4];
    const f32x4 zero4 = {0.f, 0.f, 0.f, 0.f};
    #pragma unroll
    for (int i = 0; i < 4; ++i)
        #pragma unroll
        for (int j = 0; j < 4; ++j) acc[i][j] = zero4;

    stg(0, 0);
    __syncthreads();

    int cur = 0;
    for (long k0 = 0; k0 < K; k0 += 32) {
        if (k0 + 32 < K) stg(cur ^ 1, k0 + 32);

        const unsigned short* ra = &As[cur][(wr * 64 + fr) * 32 + fk];
        const unsigned short* rb = &Bs[cur][(wc * 64 + fr) * 32 + fk];
        short8 af[4], bfr[4];
        #pragma unroll
        for (int i = 0; i < 4; ++i) af[i]  = *(const short8*)(ra + i * 512);
        #pragma unroll
        for (int j = 0; j < 4; ++j) bfr[j] = *(const short8*)(rb + j * 512);
        #pragma unroll
        for (int i = 0; i < 4; ++i)
            #pragma unroll
            for (int j = 0; j < 4; ++j)
                acc[i][j] = __builtin_amdgcn_mfma_f32_16x16x32_bf16(af[i], bfr[j], acc[i][j], 0, 0, 0);

        __syncthreads();
        cur ^= 1;
    }

    float s = 0.f, s2 = 0.f;
    const int orow = (lane >> 4) * 4;
    #pragma unroll
    for (int i = 0; i < 4; ++i) {
        const long rbase = m0 + wr * 64 + i * 16 + orow;
        #pragma unroll
        for (int j = 0; j < 4; ++j) {
            const long cidx = n0 + wc * 64 + j * 16 + fr;
            f32x4 v = acc[i][j];
            #pragma unroll
            for (int q = 0; q < 4; ++q) {
                float val = alpha * v[q];
                if constexpr (STATS) { s += val; s2 += val * val; }
                if constexpr (sizeof(OutT) == 4) C[(rbase + q) * ldc + cidx] = val;
                else                             C[(rbase + q) * ldc + cidx] = f2bf(val);
            }
        }
    }

    if constexpr (STATS) {
        float* red = (float*)&As[0][0];
        red[tid] = s; red[256 + tid] = s2;
        __syncthreads();
        for (int off = 128; off > 0; off >>= 1) {
            if (tid < off) { red[tid] += red[tid + off]; red[256 + tid] += red[256 + tid + off]; }
            __syncthreads();
        }
        if (tid == 0)
            sp_out[(long)z * 32 + blockIdx.y * gridDim.x + blockIdx.x] =
                make_float2(red[0], red[256]);
    }
}

// ---------------------------------------------------------------------------
// f32 [R][Cin] -> bf16 [Cp][R] transposed, zero-filling cols Cin..Cp-1.
// ---------------------------------------------------------------------------
__global__ __launch_bounds__(256)
void transpose_cast(const float* __restrict__ in, unsigned short* __restrict__ out,
                    int R, int Cin, int Cp, long sin_, long sout_)
{
    __shared__ float t[32][33];
    const int z = blockIdx.z;
    in  += (long)z * sin_;
    out += (long)z * sout_;
    const int r0 = blockIdx.x * 32, c0 = blockIdx.y * 32;
    const int tx = threadIdx.x & 31, ty = threadIdx.x >> 5;
    #pragma unroll
    for (int i = 0; i < 4; ++i) {
        int r = r0 + ty + i * 8, c = c0 + tx;
        t[ty + i * 8][tx] = (c < Cin) ? in[(long)r * Cin + c] : 0.f;
    }
    __syncthreads();
    #pragma unroll
    for (int i = 0; i < 4; ++i) {
        int c = c0 + ty + i * 8, r = r0 + tx;
        if (c < Cp) out[(long)c * R + r] = f2bf(t[tx][ty + i * 8]);
    }
}

// ---------------------------------------------------------------------------
// emb_all [b][4096][960] f32, ONE read -> BOTH:
//   outT [b][1024][4096] bf16 (transposed, cols>=960 zero)
//   outB [b][4096][960]  bf16 (straight cast)
// grid (128, 32, 4), block 256.
// ---------------------------------------------------------------------------
__global__ __launch_bounds__(256)
void prep_emb_all(const float* __restrict__ in, unsigned short* __restrict__ outT,
                  unsigned short* __restrict__ outB)
{
    __shared__ float t[32][33];
    const int z = blockIdx.z;
    in   += (long)z * 4096 * 960;
    outT += (long)z * 1024 * 4096;
    outB += (long)z * 4096 * 960;
    const int r0 = blockIdx.x * 32, c0 = blockIdx.y * 32;
    const int tx = threadIdx.x & 31, ty = threadIdx.x >> 5;
    #pragma unroll
    for (int i = 0; i < 4; ++i) {
        int r = r0 + ty + i * 8, c = c0 + tx;
        float v = (c < 960) ? in[(long)r * 960 + c] : 0.f;
        t[ty + i * 8][tx] = v;
        if (c < 960) outB[(long)r * 960 + c] = f2bf(v);
    }
    __syncthreads();
    #pragma unroll
    for (int i = 0; i < 4; ++i) {
        int c = c0 + ty + i * 8, r = r0 + tx;
        outT[(long)c * 4096 + r] = f2bf(t[tx][ty + i * 8]);
    }
}

// ---------------------------------------------------------------------------
// Weight casts in one launch: Wk->WkB (row-pad to 1024), Wq->WqB, Wo->WoB.
// ---------------------------------------------------------------------------
__global__ __launch_bounds__(256)
void prep_weights(const float* __restrict__ Wk, const float* __restrict__ Wq,
                  const float* __restrict__ Wo,
                  unsigned short* __restrict__ WkB, unsigned short* __restrict__ WqB,
                  unsigned short* __restrict__ WoB)
{
    long q = (long)blockIdx.x * 256 + threadIdx.x;
    if (q < 983040) {
        long e = q * 4;
        long h = e / 983040L; long r2 = e - h * 983040L;
        long r = r2 / 960;    long c = r2 - r * 960;
        ushort4 o = {0, 0, 0, 0};
        if (r < 960) {
            float4 v = *(const float4*)(Wk + (h * 960 + r) * 960 + c);
            o.x = f2bf(v.x); o.y = f2bf(v.y); o.z = f2bf(v.z); o.w = f2bf(v.w);
        }
        *(ushort4*)(WkB + e) = o;
        return;
    }
    q -= 983040;
    if (q < 262144) {
        long e = q * 4;
        float4 v = *(const float4*)(Wq + e);
        ushort4 o; o.x = f2bf(v.x); o.y = f2bf(v.y); o.z = f2bf(v.z); o.w = f2bf(v.w);
        *(ushort4*)(WqB + e) = o;
        return;
    }
    q -= 262144;
    if (q < 65536) {
        long e = q * 4;
        float4 v = *(const float4*)(Wo + e);
        ushort4 o; o.x = f2bf(v.x); o.y = f2bf(v.y); o.z = f2bf(v.z); o.w = f2bf(v.w);
        *(ushort4*)(WoB + e) = o;
    }
}

// GT[b][r] = f2bf(sum_sp partK[b][sp][r]); 4 elems/thread.
__global__ __launch_bounds__(256)
void reduce_gt(const float* __restrict__ part, unsigned short* __restrict__ GT)
{
    long i = ((long)blockIdx.x * 256 + threadIdx.x) * 4;
    long b = i >> 19, r = i & 524287;
    const float* p = part + b * 4 * 524288 + r;
    float4 s0 = *(const float4*)(p);
    float4 s1 = *(const float4*)(p + 524288);
    float4 s2 = *(const float4*)(p + 2 * 524288);
    float4 s3 = *(const float4*)(p + 3 * 524288);
    ushort4 o;
    o.x = f2bf(s0.x + s1.x + s2.x + s3.x);
    o.y = f2bf(s0.y + s1.y + s2.y + s3.y);
    o.z = f2bf(s0.z + s1.z + s2.z + s3.z);
    o.w = f2bf(s0.w + s1.w + s2.w + s3.w);
    *(ushort4*)(GT + i) = o;
}

// ---------------------------------------------------------------------------
// norm + softmax, bf16 in / bf16 out, ushort4-vectorized (G13).
// mean/rstd reduced from the 32 per-plane GEMM partials. 1 block per row.
// threads 0..239 own 4 real cols; threads 240..255 write the pad zeros.
// ---------------------------------------------------------------------------
__global__ __launch_bounds__(256)
void norm_softmax(const unsigned short* __restrict__ SC, const float2* __restrict__ part,
                  unsigned short* __restrict__ probs)
{
    const long row = blockIdx.x;
    const int z = (int)(row >> 9);
    float s0 = 0.f, s20 = 0.f;
    #pragma unroll
    for (int i = 0; i < 32; ++i) {
        float2 v = part[z * 32 + i];
        s0 += v.x; s20 += v.y;
    }
    const float ninv = 1.f / (512.f * 960.f);
    const float mean = s0 * ninv;
    const float rstd = rsqrtf(s20 * ninv - mean * mean + 960.f * 1e-5f);

    const unsigned short* p = SC + row * 1024;
    unsigned short* o = probs + row * 1024;
    const int tid = threadIdx.x;
    const bool act = tid < 240;
    const int j0 = tid * 4;

    float x[4];
    float mx = -1e30f;
    if (act) {
        ushort4 v = *(const ushort4*)(p + j0);
        x[0] = (bf2f(v.x) - mean) * rstd;
        x[1] = (bf2f(v.y) - mean) * rstd;
        x[2] = (bf2f(v.z) - mean) * rstd;
        x[3] = (bf2f(v.w) - mean) * rstd;
        mx = fmaxf(fmaxf(x[0], x[1]), fmaxf(x[2], x[3]));
    }
    __shared__ float sh[256];
    sh[tid] = mx; __syncthreads();
    for (int off = 128; off > 0; off >>= 1) {
        if (tid < off) sh[tid] = fmaxf(sh[tid], sh[tid + off]);
        __syncthreads();
    }
    mx = sh[0]; __syncthreads();
    float s = 0.f;
    if (act) {
        #pragma unroll
        for (int r = 0; r < 4; ++r) { x[r] = __expf(x[r] - mx); s += x[r]; }
    }
    sh[tid] = s; __syncthreads();
    for (int off = 128; off > 0; off >>= 1) {
        if (tid < off) sh[tid] += sh[tid + off];
        __syncthreads();
    }
    const float inv = 1.f / sh[0];
    ushort4 w = {0, 0, 0, 0};
    if (act) {
        w.x = f2bf(x[0] * inv); w.y = f2bf(x[1] * inv);
        w.z = f2bf(x[2] * inv); w.w = f2bf(x[3] * inv);
    }
    *(ushort4*)(o + j0) = w;   // tid>=240 writes the 64 pad zeros
}

// ---------------------------------------------------------------------------
// UbarT[b] = sum_h UT[b*4+h]; 8 elems/thread.
// ---------------------------------------------------------------------------
__global__ __launch_bounds__(256)
void mean_heads(const unsigned short* __restrict__ UT, unsigned short* __restrict__ Ub)
{
    const long per = 1024L * 512;
    long e = ((long)blockIdx.x * 256 + threadIdx.x) * 8;
    long b = e / per; long r = e - b * per;
    const short8 v0 = *(const short8*)(UT + (b * 4 + 0) * per + r);
    const short8 v1 = *(const short8*)(UT + (b * 4 + 1) * per + r);
    const short8 v2 = *(const short8*)(UT + (b * 4 + 2) * per + r);
    const short8 v3 = *(const short8*)(UT + (b * 4 + 3) * per + r);
    short8 o;
    #pragma unroll
    for (int k = 0; k < 8; ++k) {
        float s = bf2f((unsigned short)v0[k]) + bf2f((unsigned short)v1[k])
                + bf2f((unsigned short)v2[k]) + bf2f((unsigned short)v3[k]);
        o[k] = (short)f2bf(s);
    }
    *(short8*)(Ub + b * per + r) = o;
}

// ---------------------------------------------------------------------------
extern "C" void kernel_launch(void* const* d_in, const int* in_sizes, int n_in,
                              void* d_out, int out_size, void* d_ws, size_t ws_size,
                              hipStream_t stream)
{
    const float* emb     = (const float*)d_in[0];  // [4][4096][512]
    const float* emb_all = (const float*)d_in[1];  // [4][4096][960]
    const float* Wq      = (const float*)d_in[2];  // [4][512][512]
    const float* Wk      = (const float*)d_in[3];  // [4][960][960]
    const float* Wv      = (const float*)d_in[4];  // [4][960][960]
    const float* Wo      = (const float*)d_in[5];  // [512][512]
    float* out = (float*)d_out;

    char* ws = (char*)d_ws;
    unsigned short* embT     = (unsigned short*)(ws);              // [b][512][4096]
    unsigned short* emb_allT = (unsigned short*)(ws + 16777216);   // [b][1024][4096]
    unsigned short* emb_allB = (unsigned short*)(ws + 50331648);   // [b][4096][960]
    unsigned short* WqB      = (unsigned short*)(ws + 81788928);   // [h][512][512]
    unsigned short* WkB      = (unsigned short*)(ws + 83886080);   // [h][1024][960]
    unsigned short* WvT      = (unsigned short*)(ws + 91750400);   // [h][1024][960]
    unsigned short* WoB      = (unsigned short*)(ws + 99614720);   // [512][512]
    unsigned short* GT       = (unsigned short*)(ws + 100139008);  // [b][1024][512]
    unsigned short* probs    = (unsigned short*)(ws + 104333312);  // [z][512][1024]
    float2* sc_part          = (float2*)(ws + 121110528);          // [16][32]
    float*  partK            = (float*)(ws + 134217728);           // 32 MB

    // region reuse (sequential liveness)
    unsigned short* S1  = embT;                           // embT dead after splitk
    unsigned short* SC  = emb_allT;                       // emb_allT dead after splitk
    unsigned short* UT  = (unsigned short*)(ws + 33554432); // 2nd half of emb_allT region
    unsigned short* UbT = GT;                             // GT dead after step 2
    unsigned short* W2  = embT;                           // S1 dead after step 3

    // ---- preps (emb_all: ONE read -> transposed + straight) ----
    prep_weights<<<5120, 256, 0, stream>>>(Wk, Wq, Wo, WkB, WqB, WoB);
    transpose_cast<<<dim3(128, 16, 4), 256, 0, stream>>>(emb, embT, 4096, 512, 512, 4096L*512, 512L*4096);
    transpose_cast<<<dim3(30,  32, 4), 256, 0, stream>>>(Wv,  WvT,  960,  960, 1024, 960L*960, 1024L*960);
    prep_emb_all<<<dim3(128, 32, 4), 256, 0, stream>>>(emb_all, emb_allT, emb_allB);

    // ---- 1. split-K (z = b*4+sp): partK[z] = emb_allT chunk x embT chunk^T ----
    gemm_bt<float, false><<<dim3(4, 8, 16), 256, 0, stream>>>(
        emb_allT, embT, partK, nullptr, 1024, 4096, 4096, 512,
        1024L*4096, 1024, 512L*4096, 1024, 1024L*512, 4, 1.f);
    reduce_gt<<<2048, 256, 0, stream>>>(partK, GT);

    // ---- 2. S1[b,h] = Wq[h] x GT[b]^T  (M=512, N=1024, K=512) ----
    gemm_bt<unsigned short, false><<<dim3(8, 4, 16), 256, 0, stream>>>(
        WqB, GT, S1, nullptr, 512, 512, 512, 1024,
        0, 512L*512, 1024L*512, 0, 512L*1024, 4, 1.f);

    // ---- 3. SC[z] = S1[z] x WkB[h]^T (bf16 out) + fused stats partials ----
    gemm_bt<unsigned short, true><<<dim3(8, 4, 16), 256, 0, stream>>>(
        S1, WkB, SC, sc_part, 960, 1024, 960, 1024,
        4L*512*1024, 512L*1024, 0, 1024L*960, 512L*1024, 4, 1.f);

    // ---- 4. fused instance-norm + softmax (bf16 in/out) ----
    norm_softmax<<<8192, 256, 0, stream>>>(SC, sc_part, probs);

    // ---- 5. UT[z] = WvT[h] x probs[z]^T * 0.25  (M=1024, N=512, K=960) ----
    gemm_bt<unsigned short, false><<<dim3(4, 8, 16), 256, 0, stream>>>(
        WvT, probs, UT, nullptr, 960, 960, 1024, 512,
        0, 1024L*960, 4L*512*1024, 512L*1024, 1024L*512, 4, 0.25f);

    // ---- 6. UbT[b] = sum_h UT[b,h] ----
    mean_heads<<<1024, 256, 0, stream>>>(UT, UbT);

    // ---- 7. W2[b] = WoB x UbT[b]^T  (M=512, N=1024, K=512) ----
    gemm_bt<unsigned short, false><<<dim3(8, 4, 4), 256, 0, stream>>>(
        WoB, UbT, W2, nullptr, 512, 512, 512, 1024,
        0, 0, 1024L*512, 0, 512L*1024, 1, 1.f);

    // ---- 8. out[b] = emb_allB[b] x W2[b]^T  (M=4096, N=512, K=960) ----
    gemm_bt<float, false><<<dim3(4, 32, 4), 256, 0, stream>>>(
        emb_allB, W2, out, nullptr, 960, 960, 1024, 512,
        4096L*960, 0, 512L*1024, 0, 4096L*512, 1, 1.f);
}

// Round 6
// 226.581 us; speedup vs baseline: 11.1665x; 1.0633x over previous
//
#include <hip/hip_runtime.h>
#include <math.h>

typedef __attribute__((ext_vector_type(8))) short short8;
typedef __attribute__((ext_vector_type(4))) float f32x4;

__device__ __forceinline__ unsigned short f2bf(float f) {
    unsigned int u; __builtin_memcpy(&u, &f, 4);
    unsigned int r = (u + 0x7FFFu + ((u >> 16) & 1u)) >> 16;
    return (unsigned short)r;
}
__device__ __forceinline__ float bf2f(unsigned short h) {
    unsigned int u = ((unsigned int)h) << 16;
    float f; __builtin_memcpy(&f, &u, 4); return f;
}
__device__ __forceinline__ void gl2lds16(const unsigned short* g, unsigned short* l) {
    __builtin_amdgcn_global_load_lds(
        (const __attribute__((address_space(1))) unsigned int*)g,
        (__attribute__((address_space(3))) unsigned int*)l, 16, 0, 0);
}

// ---------------------------------------------------------------------------
// bf16 MFMA GEMM, double-buffered 2-phase pipeline.
// C[m][n] = alpha * sum_k A[m,k]*B[n,k]; tile 128x128, BK=32, 4 waves.
// STATS: also emit per-block (sum, sumsq) fp32 partials for InstanceNorm.
// ---------------------------------------------------------------------------
template<typename OutT, bool STATS>
__global__ __launch_bounds__(256)
void gemm_bt(const unsigned short* __restrict__ A, const unsigned short* __restrict__ B,
             OutT* __restrict__ C, float2* __restrict__ sp_out,
             int K, long lda, long ldb, long ldc,
             long sa_bb, long sa_bh, long sb_bb, long sb_bh, long sc_z,
             int H, float alpha)
{
    __shared__ unsigned short As[2][128 * 32];
    __shared__ unsigned short Bs[2][128 * 32];

    const int z = blockIdx.z;
    const int bb = z / H, hh = z - bb * H;
    A += (long)bb * sa_bb + (long)hh * sa_bh;
    B += (long)bb * sb_bb + (long)hh * sb_bh;
    C += (long)z * sc_z;

    const int tid  = threadIdx.x;
    const int lane = tid & 63;
    const int wave = tid >> 6;
    const int wr = wave >> 1, wc = wave & 1;

    const long m0 = (long)blockIdx.y * 128;
    const long n0 = (long)blockIdx.x * 128;

    const int ch0  = wave * 2;
    const int lrow = lane >> 2;
    const int lcol = (lane & 3) * 8;
    const unsigned short* ga0 = A + (m0 + ch0 * 16 + lrow) * lda + lcol;
    const unsigned short* ga1 = ga0 + 16 * lda;
    const unsigned short* gb0 = B + (n0 + ch0 * 16 + lrow) * ldb + lcol;
    const unsigned short* gb1 = gb0 + 16 * ldb;

    auto stg = [&](int buf, long koff) {
        gl2lds16(ga0 + koff, &As[buf][ch0 * 512]);
        gl2lds16(ga1 + koff, &As[buf][ch0 * 512 + 512]);
        gl2lds16(gb0 + koff, &Bs[buf][ch0 * 512]);
        gl2lds16(gb1 + koff, &Bs[buf][ch0 * 512 + 512]);
    };

    const int fr = lane & 15;
    const int fk = (lane >> 4) * 8;

    f32x4 acc[4][4];
    const f32x4 zero4 = {0.f, 0.f, 0.f, 0.f};
    #pragma unroll
    for (int i = 0; i < 4; ++i)
        #pragma unroll
        for (int j = 0; j < 4; ++j) acc[i][j] = zero4;

    stg(0, 0);
    __syncthreads();

    int cur = 0;
    for (long k0 = 0; k0 < K; k0 += 32) {
        if (k0 + 32 < K) stg(cur ^ 1, k0 + 32);

        const unsigned short* ra = &As[cur][(wr * 64 + fr) * 32 + fk];
        const unsigned short* rb = &Bs[cur][(wc * 64 + fr) * 32 + fk];
        short8 af[4], bfr[4];
        #pragma unroll
        for (int i = 0; i < 4; ++i) af[i]  = *(const short8*)(ra + i * 512);
        #pragma unroll
        for (int j = 0; j < 4; ++j) bfr[j] = *(const short8*)(rb + j * 512);
        #pragma unroll
        for (int i = 0; i < 4; ++i)
            #pragma unroll
            for (int j = 0; j < 4; ++j)
                acc[i][j] = __builtin_amdgcn_mfma_f32_16x16x32_bf16(af[i], bfr[j], acc[i][j], 0, 0, 0);

        __syncthreads();
        cur ^= 1;
    }

    float s = 0.f, s2 = 0.f;
    const int orow = (lane >> 4) * 4;
    #pragma unroll
    for (int i = 0; i < 4; ++i) {
        const long rbase = m0 + wr * 64 + i * 16 + orow;
        #pragma unroll
        for (int j = 0; j < 4; ++j) {
            const long cidx = n0 + wc * 64 + j * 16 + fr;
            f32x4 v = acc[i][j];
            #pragma unroll
            for (int q = 0; q < 4; ++q) {
                float val = alpha * v[q];
                if constexpr (STATS) { s += val; s2 += val * val; }
                if constexpr (sizeof(OutT) == 4) C[(rbase + q) * ldc + cidx] = val;
                else                             C[(rbase + q) * ldc + cidx] = f2bf(val);
            }
        }
    }

    if constexpr (STATS) {
        float* red = (float*)&As[0][0];
        red[tid] = s; red[256 + tid] = s2;
        __syncthreads();
        for (int off = 128; off > 0; off >>= 1) {
            if (tid < off) { red[tid] += red[tid + off]; red[256 + tid] += red[256 + tid + off]; }
            __syncthreads();
        }
        if (tid == 0)
            sp_out[(long)z * 32 + blockIdx.y * gridDim.x + blockIdx.x] =
                make_float2(red[0], red[256]);
    }
}

// ---------------------------------------------------------------------------
// Vectorized transpose-cast, 64x64 tiles (G13-compliant):
//   in  f32 [R][Cin]  ->  outT bf16 [Cp][R]  (cols >= Cin zero-filled)
//   DUAL: also outB bf16 [R][Cin] (straight cast; single global read)
// float4 reads, ushort4 writes. Tiles are 64-aligned; Cin,Cp multiples of 64.
// grid (R/64, Cp/64, Z), block 256.
// ---------------------------------------------------------------------------
template<bool DUAL>
__global__ __launch_bounds__(256)
void transpose_cast64(const float* __restrict__ in, unsigned short* __restrict__ outT,
                      unsigned short* __restrict__ outB,
                      int R, int Cin, long sin_, long soutT, long soutB)
{
    __shared__ float t[64][65];
    const int z = blockIdx.z;
    in   += (long)z * sin_;
    outT += (long)z * soutT;
    if constexpr (DUAL) outB += (long)z * soutB;
    const int r0 = blockIdx.x * 64, c0 = blockIdx.y * 64;
    const int tid = threadIdx.x;
    const int rr  = tid >> 4;          // 0..15
    const int cc4 = (tid & 15) * 4;    // elem offset within tile
    const bool real = (c0 + cc4) < Cin;   // 64-aligned: whole tile real or pad

    #pragma unroll
    for (int i = 0; i < 4; ++i) {
        const int r = rr + i * 16;
        float4 v = make_float4(0.f, 0.f, 0.f, 0.f);
        if (real) v = *(const float4*)(in + (long)(r0 + r) * Cin + c0 + cc4);
        t[r][cc4] = v.x; t[r][cc4 + 1] = v.y; t[r][cc4 + 2] = v.z; t[r][cc4 + 3] = v.w;
        if constexpr (DUAL) {
            if (real) {
                ushort4 o;
                o.x = f2bf(v.x); o.y = f2bf(v.y); o.z = f2bf(v.z); o.w = f2bf(v.w);
                *(ushort4*)(outB + (long)(r0 + r) * Cin + c0 + cc4) = o;
            }
        }
    }
    __syncthreads();
    #pragma unroll
    for (int i = 0; i < 4; ++i) {
        const int c = rr + i * 16;
        ushort4 o;
        o.x = f2bf(t[cc4 + 0][c]);
        o.y = f2bf(t[cc4 + 1][c]);
        o.z = f2bf(t[cc4 + 2][c]);
        o.w = f2bf(t[cc4 + 3][c]);
        *(ushort4*)(outT + (long)(c0 + c) * R + r0 + cc4) = o;
    }
}

// ---------------------------------------------------------------------------
// Weight casts in one launch: Wk->WkB (row-pad to 1024), Wq->WqB, Wo->WoB.
// ---------------------------------------------------------------------------
__global__ __launch_bounds__(256)
void prep_weights(const float* __restrict__ Wk, const float* __restrict__ Wq,
                  const float* __restrict__ Wo,
                  unsigned short* __restrict__ WkB, unsigned short* __restrict__ WqB,
                  unsigned short* __restrict__ WoB)
{
    long q = (long)blockIdx.x * 256 + threadIdx.x;
    if (q < 983040) {
        long e = q * 4;
        long h = e / 983040L; long r2 = e - h * 983040L;
        long r = r2 / 960;    long c = r2 - r * 960;
        ushort4 o = {0, 0, 0, 0};
        if (r < 960) {
            float4 v = *(const float4*)(Wk + (h * 960 + r) * 960 + c);
            o.x = f2bf(v.x); o.y = f2bf(v.y); o.z = f2bf(v.z); o.w = f2bf(v.w);
        }
        *(ushort4*)(WkB + e) = o;
        return;
    }
    q -= 983040;
    if (q < 262144) {
        long e = q * 4;
        float4 v = *(const float4*)(Wq + e);
        ushort4 o; o.x = f2bf(v.x); o.y = f2bf(v.y); o.z = f2bf(v.z); o.w = f2bf(v.w);
        *(ushort4*)(WqB + e) = o;
        return;
    }
    q -= 262144;
    if (q < 65536) {
        long e = q * 4;
        float4 v = *(const float4*)(Wo + e);
        ushort4 o; o.x = f2bf(v.x); o.y = f2bf(v.y); o.z = f2bf(v.z); o.w = f2bf(v.w);
        *(ushort4*)(WoB + e) = o;
    }
}

// GT[b][r] = f2bf(sum_sp partK[b][sp][r]); 4 elems/thread.
__global__ __launch_bounds__(256)
void reduce_gt(const float* __restrict__ part, unsigned short* __restrict__ GT)
{
    long i = ((long)blockIdx.x * 256 + threadIdx.x) * 4;
    long b = i >> 19, r = i & 524287;
    const float* p = part + b * 4 * 524288 + r;
    float4 s0 = *(const float4*)(p);
    float4 s1 = *(const float4*)(p + 524288);
    float4 s2 = *(const float4*)(p + 2 * 524288);
    float4 s3 = *(const float4*)(p + 3 * 524288);
    ushort4 o;
    o.x = f2bf(s0.x + s1.x + s2.x + s3.x);
    o.y = f2bf(s0.y + s1.y + s2.y + s3.y);
    o.z = f2bf(s0.z + s1.z + s2.z + s3.z);
    o.w = f2bf(s0.w + s1.w + s2.w + s3.w);
    *(ushort4*)(GT + i) = o;
}

// ---------------------------------------------------------------------------
// norm + softmax, bf16 in / bf16 out, ushort4-vectorized.
// mean/rstd reduced from the 32 per-plane GEMM partials. 1 block per row.
// threads 0..239 own 4 real cols; threads 240..255 write the pad zeros.
// ---------------------------------------------------------------------------
__global__ __launch_bounds__(256)
void norm_softmax(const unsigned short* __restrict__ SC, const float2* __restrict__ part,
                  unsigned short* __restrict__ probs)
{
    const long row = blockIdx.x;
    const int z = (int)(row >> 9);
    float s0 = 0.f, s20 = 0.f;
    #pragma unroll
    for (int i = 0; i < 32; ++i) {
        float2 v = part[z * 32 + i];
        s0 += v.x; s20 += v.y;
    }
    const float ninv = 1.f / (512.f * 960.f);
    const float mean = s0 * ninv;
    const float rstd = rsqrtf(s20 * ninv - mean * mean + 960.f * 1e-5f);

    const unsigned short* p = SC + row * 1024;
    unsigned short* o = probs + row * 1024;
    const int tid = threadIdx.x;
    const bool act = tid < 240;
    const int j0 = tid * 4;

    float x[4];
    float mx = -1e30f;
    if (act) {
        ushort4 v = *(const ushort4*)(p + j0);
        x[0] = (bf2f(v.x) - mean) * rstd;
        x[1] = (bf2f(v.y) - mean) * rstd;
        x[2] = (bf2f(v.z) - mean) * rstd;
        x[3] = (bf2f(v.w) - mean) * rstd;
        mx = fmaxf(fmaxf(x[0], x[1]), fmaxf(x[2], x[3]));
    }
    __shared__ float sh[256];
    sh[tid] = mx; __syncthreads();
    for (int off = 128; off > 0; off >>= 1) {
        if (tid < off) sh[tid] = fmaxf(sh[tid], sh[tid + off]);
        __syncthreads();
    }
    mx = sh[0]; __syncthreads();
    float s = 0.f;
    if (act) {
        #pragma unroll
        for (int r = 0; r < 4; ++r) { x[r] = __expf(x[r] - mx); s += x[r]; }
    }
    sh[tid] = s; __syncthreads();
    for (int off = 128; off > 0; off >>= 1) {
        if (tid < off) sh[tid] += sh[tid + off];
        __syncthreads();
    }
    const float inv = 1.f / sh[0];
    ushort4 w = {0, 0, 0, 0};
    if (act) {
        w.x = f2bf(x[0] * inv); w.y = f2bf(x[1] * inv);
        w.z = f2bf(x[2] * inv); w.w = f2bf(x[3] * inv);
    }
    *(ushort4*)(o + j0) = w;
}

// ---------------------------------------------------------------------------
// UbarT[b] = sum_h UT[b*4+h]; 8 elems/thread.
// ---------------------------------------------------------------------------
__global__ __launch_bounds__(256)
void mean_heads(const unsigned short* __restrict__ UT, unsigned short* __restrict__ Ub)
{
    const long per = 1024L * 512;
    long e = ((long)blockIdx.x * 256 + threadIdx.x) * 8;
    long b = e / per; long r = e - b * per;
    const short8 v0 = *(const short8*)(UT + (b * 4 + 0) * per + r);
    const short8 v1 = *(const short8*)(UT + (b * 4 + 1) * per + r);
    const short8 v2 = *(const short8*)(UT + (b * 4 + 2) * per + r);
    const short8 v3 = *(const short8*)(UT + (b * 4 + 3) * per + r);
    short8 o;
    #pragma unroll
    for (int k = 0; k < 8; ++k) {
        float s = bf2f((unsigned short)v0[k]) + bf2f((unsigned short)v1[k])
                + bf2f((unsigned short)v2[k]) + bf2f((unsigned short)v3[k]);
        o[k] = (short)f2bf(s);
    }
    *(short8*)(Ub + b * per + r) = o;
}

// ---------------------------------------------------------------------------
extern "C" void kernel_launch(void* const* d_in, const int* in_sizes, int n_in,
                              void* d_out, int out_size, void* d_ws, size_t ws_size,
                              hipStream_t stream)
{
    const float* emb     = (const float*)d_in[0];  // [4][4096][512]
    const float* emb_all = (const float*)d_in[1];  // [4][4096][960]
    const float* Wq      = (const float*)d_in[2];  // [4][512][512]
    const float* Wk      = (const float*)d_in[3];  // [4][960][960]
    const float* Wv      = (const float*)d_in[4];  // [4][960][960]
    const float* Wo      = (const float*)d_in[5];  // [512][512]
    float* out = (float*)d_out;

    char* ws = (char*)d_ws;
    unsigned short* embT     = (unsigned short*)(ws);              // [b][512][4096]
    unsigned short* emb_allT = (unsigned short*)(ws + 16777216);   // [b][1024][4096]
    unsigned short* emb_allB = (unsigned short*)(ws + 50331648);   // [b][4096][960]
    unsigned short* WqB      = (unsigned short*)(ws + 81788928);   // [h][512][512]
    unsigned short* WkB      = (unsigned short*)(ws + 83886080);   // [h][1024][960]
    unsigned short* WvT      = (unsigned short*)(ws + 91750400);   // [h][1024][960]
    unsigned short* WoB      = (unsigned short*)(ws + 99614720);   // [512][512]
    unsigned short* GT       = (unsigned short*)(ws + 100139008);  // [b][1024][512]
    unsigned short* probs    = (unsigned short*)(ws + 104333312);  // [z][512][1024]
    float2* sc_part          = (float2*)(ws + 121110528);          // [16][32]
    float*  partK            = (float*)(ws + 134217728);           // 32 MB

    // region reuse (sequential liveness)
    unsigned short* S1  = embT;                             // embT dead after splitk
    unsigned short* SC  = emb_allT;                         // emb_allT dead after splitk
    unsigned short* UT  = (unsigned short*)(ws + 33554432); // 2nd half of emb_allT region
    unsigned short* UbT = GT;                               // GT dead after step 2
    unsigned short* W2  = embT;                             // S1 dead after step 3

    // ---- preps (vectorized 64x64 transposes; emb_all one read -> both) ----
    prep_weights<<<5120, 256, 0, stream>>>(Wk, Wq, Wo, WkB, WqB, WoB);
    transpose_cast64<false><<<dim3(64, 8, 4), 256, 0, stream>>>(
        emb, embT, nullptr, 4096, 512, 4096L*512, 512L*4096, 0);
    transpose_cast64<false><<<dim3(15, 16, 4), 256, 0, stream>>>(
        Wv, WvT, nullptr, 960, 960, 960L*960, 1024L*960, 0);
    transpose_cast64<true><<<dim3(64, 16, 4), 256, 0, stream>>>(
        emb_all, emb_allT, emb_allB, 4096, 960, 4096L*960, 1024L*4096, 4096L*960);

    // ---- 1. split-K (z = b*4+sp): partK[z] = emb_allT chunk x embT chunk^T ----
    gemm_bt<float, false><<<dim3(4, 8, 16), 256, 0, stream>>>(
        emb_allT, embT, partK, nullptr, 1024, 4096, 4096, 512,
        1024L*4096, 1024, 512L*4096, 1024, 1024L*512, 4, 1.f);
    reduce_gt<<<2048, 256, 0, stream>>>(partK, GT);

    // ---- 2. S1[b,h] = Wq[h] x GT[b]^T  (M=512, N=1024, K=512) ----
    gemm_bt<unsigned short, false><<<dim3(8, 4, 16), 256, 0, stream>>>(
        WqB, GT, S1, nullptr, 512, 512, 512, 1024,
        0, 512L*512, 1024L*512, 0, 512L*1024, 4, 1.f);

    // ---- 3. SC[z] = S1[z] x WkB[h]^T (bf16 out) + fused stats partials ----
    gemm_bt<unsigned short, true><<<dim3(8, 4, 16), 256, 0, stream>>>(
        S1, WkB, SC, sc_part, 960, 1024, 960, 1024,
        4L*512*1024, 512L*1024, 0, 1024L*960, 512L*1024, 4, 1.f);

    // ---- 4. fused instance-norm + softmax (bf16 in/out) ----
    norm_softmax<<<8192, 256, 0, stream>>>(SC, sc_part, probs);

    // ---- 5. UT[z] = WvT[h] x probs[z]^T * 0.25  (M=1024, N=512, K=960) ----
    gemm_bt<unsigned short, false><<<dim3(4, 8, 16), 256, 0, stream>>>(
        WvT, probs, UT, nullptr, 960, 960, 1024, 512,
        0, 1024L*960, 4L*512*1024, 512L*1024, 1024L*512, 4, 0.25f);

    // ---- 6. UbT[b] = sum_h UT[b,h] ----
    mean_heads<<<1024, 256, 0, stream>>>(UT, UbT);

    // ---- 7. W2[b] = WoB x UbT[b]^T  (M=512, N=1024, K=512) ----
    gemm_bt<unsigned short, false><<<dim3(8, 4, 4), 256, 0, stream>>>(
        WoB, UbT, W2, nullptr, 512, 512, 512, 1024,
        0, 0, 1024L*512, 0, 512L*1024, 1, 1.f);

    // ---- 8. out[b] = emb_allB[b] x W2[b]^T  (M=4096, N=512, K=960) ----
    gemm_bt<float, false><<<dim3(4, 32, 4), 256, 0, stream>>>(
        emb_allB, W2, out, nullptr, 960, 960, 1024, 512,
        4096L*960, 0, 512L*1024, 0, 4096L*512, 1, 1.f);
}

// Round 7
// 209.260 us; speedup vs baseline: 12.0907x; 1.0828x over previous
//
#include <hip/hip_runtime.h>
#include <math.h>

typedef __attribute__((ext_vector_type(8))) short short8;
typedef __attribute__((ext_vector_type(4))) float f32x4;

__device__ __forceinline__ unsigned short f2bf(float f) {
    unsigned int u; __builtin_memcpy(&u, &f, 4);
    unsigned int r = (u + 0x7FFFu + ((u >> 16) & 1u)) >> 16;
    return (unsigned short)r;
}
__device__ __forceinline__ float bf2f(unsigned short h) {
    unsigned int u = ((unsigned int)h) << 16;
    float f; __builtin_memcpy(&f, &u, 4); return f;
}
__device__ __forceinline__ void gl2lds16(const unsigned short* g, unsigned short* l) {
    __builtin_amdgcn_global_load_lds(
        (const __attribute__((address_space(1))) unsigned int*)g,
        (__attribute__((address_space(3))) unsigned int*)l, 16, 0, 0);
}

// ---------------------------------------------------------------------------
// bf16 MFMA GEMM, double-buffered 2-phase pipeline.
// C[m][n] = alpha * sum_k A[m,k]*B[n,k]; tile 128x128, BK=32, 4 waves.
// STATS: also emit per-block (sum, sumsq) fp32 partials for InstanceNorm.
// ---------------------------------------------------------------------------
template<typename OutT, bool STATS>
__global__ __launch_bounds__(256)
void gemm_bt(const unsigned short* __restrict__ A, const unsigned short* __restrict__ B,
             OutT* __restrict__ C, float2* __restrict__ sp_out,
             int K, long lda, long ldb, long ldc,
             long sa_bb, long sa_bh, long sb_bb, long sb_bh, long sc_z,
             int H, float alpha)
{
    __shared__ unsigned short As[2][128 * 32];
    __shared__ unsigned short Bs[2][128 * 32];

    const int z = blockIdx.z;
    const int bb = z / H, hh = z - bb * H;
    A += (long)bb * sa_bb + (long)hh * sa_bh;
    B += (long)bb * sb_bb + (long)hh * sb_bh;
    C += (long)z * sc_z;

    const int tid  = threadIdx.x;
    const int lane = tid & 63;
    const int wave = tid >> 6;
    const int wr = wave >> 1, wc = wave & 1;

    const long m0 = (long)blockIdx.y * 128;
    const long n0 = (long)blockIdx.x * 128;

    const int ch0  = wave * 2;
    const int lrow = lane >> 2;
    const int lcol = (lane & 3) * 8;
    const unsigned short* ga0 = A + (m0 + ch0 * 16 + lrow) * lda + lcol;
    const unsigned short* ga1 = ga0 + 16 * lda;
    const unsigned short* gb0 = B + (n0 + ch0 * 16 + lrow) * ldb + lcol;
    const unsigned short* gb1 = gb0 + 16 * ldb;

    auto stg = [&](int buf, long koff) {
        gl2lds16(ga0 + koff, &As[buf][ch0 * 512]);
        gl2lds16(ga1 + koff, &As[buf][ch0 * 512 + 512]);
        gl2lds16(gb0 + koff, &Bs[buf][ch0 * 512]);
        gl2lds16(gb1 + koff, &Bs[buf][ch0 * 512 + 512]);
    };

    const int fr = lane & 15;
    const int fk = (lane >> 4) * 8;

    f32x4 acc[4][4];
    const f32x4 zero4 = {0.f, 0.f, 0.f, 0.f};
    #pragma unroll
    for (int i = 0; i < 4; ++i)
        #pragma unroll
        for (int j = 0; j < 4; ++j) acc[i][j] = zero4;

    stg(0, 0);
    __syncthreads();

    int cur = 0;
    for (long k0 = 0; k0 < K; k0 += 32) {
        if (k0 + 32 < K) stg(cur ^ 1, k0 + 32);

        const unsigned short* ra = &As[cur][(wr * 64 + fr) * 32 + fk];
        const unsigned short* rb = &Bs[cur][(wc * 64 + fr) * 32 + fk];
        short8 af[4], bfr[4];
        #pragma unroll
        for (int i = 0; i < 4; ++i) af[i]  = *(const short8*)(ra + i * 512);
        #pragma unroll
        for (int j = 0; j < 4; ++j) bfr[j] = *(const short8*)(rb + j * 512);
        #pragma unroll
        for (int i = 0; i < 4; ++i)
            #pragma unroll
            for (int j = 0; j < 4; ++j)
                acc[i][j] = __builtin_amdgcn_mfma_f32_16x16x32_bf16(af[i], bfr[j], acc[i][j], 0, 0, 0);

        __syncthreads();
        cur ^= 1;
    }

    float s = 0.f, s2 = 0.f;
    const int orow = (lane >> 4) * 4;
    #pragma unroll
    for (int i = 0; i < 4; ++i) {
        const long rbase = m0 + wr * 64 + i * 16 + orow;
        #pragma unroll
        for (int j = 0; j < 4; ++j) {
            const long cidx = n0 + wc * 64 + j * 16 + fr;
            f32x4 v = acc[i][j];
            #pragma unroll
            for (int q = 0; q < 4; ++q) {
                float val = alpha * v[q];
                if constexpr (STATS) { s += val; s2 += val * val; }
                if constexpr (sizeof(OutT) == 4) C[(rbase + q) * ldc + cidx] = val;
                else                             C[(rbase + q) * ldc + cidx] = f2bf(val);
            }
        }
    }

    if constexpr (STATS) {
        float* red = (float*)&As[0][0];
        red[tid] = s; red[256 + tid] = s2;
        __syncthreads();
        for (int off = 128; off > 0; off >>= 1) {
            if (tid < off) { red[tid] += red[tid + off]; red[256 + tid] += red[256 + tid + off]; }
            __syncthreads();
        }
        if (tid == 0)
            sp_out[(long)z * 32 + blockIdx.y * gridDim.x + blockIdx.x] =
                make_float2(red[0], red[256]);
    }
}

// ---------------------------------------------------------------------------
// 64x64 vectorized transpose-cast worker (float4 read, ushort4 writes).
// in f32 [R][Cin] -> outT bf16 [Cp][R]; optional outB bf16 [R][Cin].
// ---------------------------------------------------------------------------
__device__ __forceinline__
void tc64_impl(const float* __restrict__ in, unsigned short* __restrict__ outT,
               unsigned short* __restrict__ outB, int R, int Cin,
               int bx, int by, bool dual, float (*t)[65])
{
    const int r0 = bx * 64, c0 = by * 64;
    const int tid = threadIdx.x;
    const int rr  = tid >> 4;
    const int cc4 = (tid & 15) * 4;
    const bool real = (c0 + cc4) < Cin;

    #pragma unroll
    for (int i = 0; i < 4; ++i) {
        const int r = rr + i * 16;
        float4 v = make_float4(0.f, 0.f, 0.f, 0.f);
        if (real) v = *(const float4*)(in + (long)(r0 + r) * Cin + c0 + cc4);
        t[r][cc4] = v.x; t[r][cc4 + 1] = v.y; t[r][cc4 + 2] = v.z; t[r][cc4 + 3] = v.w;
        if (dual && real) {
            ushort4 o;
            o.x = f2bf(v.x); o.y = f2bf(v.y); o.z = f2bf(v.z); o.w = f2bf(v.w);
            *(ushort4*)(outB + (long)(r0 + r) * Cin + c0 + cc4) = o;
        }
    }
    __syncthreads();
    #pragma unroll
    for (int i = 0; i < 4; ++i) {
        const int c = rr + i * 16;
        ushort4 o;
        o.x = f2bf(t[cc4 + 0][c]);
        o.y = f2bf(t[cc4 + 1][c]);
        o.z = f2bf(t[cc4 + 2][c]);
        o.w = f2bf(t[cc4 + 3][c]);
        *(ushort4*)(outT + (long)(c0 + c) * R + r0 + cc4) = o;
    }
}

// ---------------------------------------------------------------------------
// ALL preps in one launch (block-range segmented):
//  [0,4096)        dual emb_all: emb_allT (transposed, pad) + emb_allB (cast)
//  [4096,6144)     embT transpose
//  [6144,7104)     WvT transpose (pad cols to 1024)
//  [7104,12224)    weight casts: WkB (row-pad 1024), WqB, WoB
// ---------------------------------------------------------------------------
__global__ __launch_bounds__(256)
void prep_all(const float* __restrict__ emb, const float* __restrict__ emb_all,
              const float* __restrict__ Wq, const float* __restrict__ Wk,
              const float* __restrict__ Wv, const float* __restrict__ Wo,
              unsigned short* __restrict__ embT, unsigned short* __restrict__ emb_allT,
              unsigned short* __restrict__ emb_allB, unsigned short* __restrict__ WqB,
              unsigned short* __restrict__ WkB, unsigned short* __restrict__ WvT,
              unsigned short* __restrict__ WoB)
{
    __shared__ float t[64][65];
    int bid = blockIdx.x;
    if (bid < 4096) {
        const int z = bid >> 10, r2 = bid & 1023, by = r2 >> 6, bx = r2 & 63;
        tc64_impl(emb_all + (long)z * 4096 * 960, emb_allT + (long)z * 1024 * 4096,
                  emb_allB + (long)z * 4096 * 960, 4096, 960, bx, by, true, t);
        return;
    }
    bid -= 4096;
    if (bid < 2048) {
        const int z = bid >> 9, r2 = bid & 511, by = r2 >> 6, bx = r2 & 63;
        tc64_impl(emb + (long)z * 4096 * 512, embT + (long)z * 512 * 4096,
                  nullptr, 4096, 512, bx, by, false, t);
        return;
    }
    bid -= 2048;
    if (bid < 960) {
        const int z = bid / 240, r2 = bid % 240, by = r2 / 15, bx = r2 % 15;
        tc64_impl(Wv + (long)z * 960 * 960, WvT + (long)z * 1024 * 960,
                  nullptr, 960, 960, bx, by, false, t);
        return;
    }
    bid -= 960;
    long q = (long)bid * 256 + threadIdx.x;
    if (q < 983040) {                       // WkB
        long e = q * 4;
        long h = e / 983040L; long r2 = e - h * 983040L;
        long r = r2 / 960;    long c = r2 - r * 960;
        ushort4 o = {0, 0, 0, 0};
        if (r < 960) {
            float4 v = *(const float4*)(Wk + (h * 960 + r) * 960 + c);
            o.x = f2bf(v.x); o.y = f2bf(v.y); o.z = f2bf(v.z); o.w = f2bf(v.w);
        }
        *(ushort4*)(WkB + e) = o;
        return;
    }
    q -= 983040;
    if (q < 262144) {                       // WqB
        long e = q * 4;
        float4 v = *(const float4*)(Wq + e);
        ushort4 o; o.x = f2bf(v.x); o.y = f2bf(v.y); o.z = f2bf(v.z); o.w = f2bf(v.w);
        *(ushort4*)(WqB + e) = o;
        return;
    }
    q -= 262144;
    if (q < 65536) {                        // WoB
        long e = q * 4;
        float4 v = *(const float4*)(Wo + e);
        ushort4 o; o.x = f2bf(v.x); o.y = f2bf(v.y); o.z = f2bf(v.z); o.w = f2bf(v.w);
        *(ushort4*)(WoB + e) = o;
    }
}

// GT[b][r] = f2bf(sum_sp bf16 partK[b][sp][r]); 8 elems/thread, 1024 blocks.
__global__ __launch_bounds__(256)
void reduce_gt(const unsigned short* __restrict__ part, unsigned short* __restrict__ GT)
{
    long i = ((long)blockIdx.x * 256 + threadIdx.x) * 8;
    long b = i >> 19, r = i & 524287;
    const unsigned short* p = part + b * 4 * 524288 + r;
    const short8 v0 = *(const short8*)(p);
    const short8 v1 = *(const short8*)(p + 524288);
    const short8 v2 = *(const short8*)(p + 2 * 524288);
    const short8 v3 = *(const short8*)(p + 3 * 524288);
    short8 o;
    #pragma unroll
    for (int k = 0; k < 8; ++k) {
        float s = bf2f((unsigned short)v0[k]) + bf2f((unsigned short)v1[k])
                + bf2f((unsigned short)v2[k]) + bf2f((unsigned short)v3[k]);
        o[k] = (short)f2bf(s);
    }
    *(short8*)(GT + i) = o;
}

// ---------------------------------------------------------------------------
// norm + softmax, one WAVE per row (shfl-only reductions, no __syncthreads).
// 4 waves/block, 2048 blocks. Lane owns 16 cols; lanes 60..63 are pad.
// ---------------------------------------------------------------------------
__global__ __launch_bounds__(256)
void norm_softmax(const unsigned short* __restrict__ SC, const float2* __restrict__ part,
                  unsigned short* __restrict__ probs)
{
    const int lane = threadIdx.x & 63;
    const int wave = threadIdx.x >> 6;
    const long row = (long)blockIdx.x * 4 + wave;
    const int z = (int)(row >> 9);

    // stats: lane-parallel partial load + 32-lane butterfly
    float2 pv = part[z * 32 + (lane & 31)];
    float a = pv.x, b = pv.y;
    #pragma unroll
    for (int off = 1; off < 32; off <<= 1) {
        a += __shfl_xor(a, off);
        b += __shfl_xor(b, off);
    }
    const float ninv = 1.f / (512.f * 960.f);
    const float mean = a * ninv;
    const float rstd = rsqrtf(b * ninv - mean * mean + 960.f * 1e-5f);

    const unsigned short* p = SC + row * 1024 + lane * 16;
    const bool act = lane < 60;
    float x[16];
    {
        const short8 w0 = *(const short8*)(p);
        const short8 w1 = *(const short8*)(p + 8);
        #pragma unroll
        for (int k = 0; k < 8; ++k) {
            x[k]     = (bf2f((unsigned short)w0[k]) - mean) * rstd;
            x[k + 8] = (bf2f((unsigned short)w1[k]) - mean) * rstd;
        }
    }
    float mx = -1e30f;
    if (act) {
        #pragma unroll
        for (int k = 0; k < 16; ++k) mx = fmaxf(mx, x[k]);
    }
    #pragma unroll
    for (int off = 1; off < 64; off <<= 1) mx = fmaxf(mx, __shfl_xor(mx, off));

    float s = 0.f;
    if (act) {
        #pragma unroll
        for (int k = 0; k < 16; ++k) { x[k] = __expf(x[k] - mx); s += x[k]; }
    }
    #pragma unroll
    for (int off = 1; off < 64; off <<= 1) s += __shfl_xor(s, off);
    const float inv = 1.f / s;

    unsigned short* o = probs + row * 1024 + lane * 16;
    short8 o0 = {0,0,0,0,0,0,0,0}, o1 = {0,0,0,0,0,0,0,0};
    if (act) {
        #pragma unroll
        for (int k = 0; k < 8; ++k) {
            o0[k] = (short)f2bf(x[k] * inv);
            o1[k] = (short)f2bf(x[k + 8] * inv);
        }
    }
    *(short8*)(o)     = o0;
    *(short8*)(o + 8) = o1;
}

// ---------------------------------------------------------------------------
// UbarT[b] = sum_h UT[b*4+h]; 8 elems/thread.
// ---------------------------------------------------------------------------
__global__ __launch_bounds__(256)
void mean_heads(const unsigned short* __restrict__ UT, unsigned short* __restrict__ Ub)
{
    const long per = 1024L * 512;
    long e = ((long)blockIdx.x * 256 + threadIdx.x) * 8;
    long b = e / per; long r = e - b * per;
    const short8 v0 = *(const short8*)(UT + (b * 4 + 0) * per + r);
    const short8 v1 = *(const short8*)(UT + (b * 4 + 1) * per + r);
    const short8 v2 = *(const short8*)(UT + (b * 4 + 2) * per + r);
    const short8 v3 = *(const short8*)(UT + (b * 4 + 3) * per + r);
    short8 o;
    #pragma unroll
    for (int k = 0; k < 8; ++k) {
        float s = bf2f((unsigned short)v0[k]) + bf2f((unsigned short)v1[k])
                + bf2f((unsigned short)v2[k]) + bf2f((unsigned short)v3[k]);
        o[k] = (short)f2bf(s);
    }
    *(short8*)(Ub + b * per + r) = o;
}

// ---------------------------------------------------------------------------
extern "C" void kernel_launch(void* const* d_in, const int* in_sizes, int n_in,
                              void* d_out, int out_size, void* d_ws, size_t ws_size,
                              hipStream_t stream)
{
    const float* emb     = (const float*)d_in[0];  // [4][4096][512]
    const float* emb_all = (const float*)d_in[1];  // [4][4096][960]
    const float* Wq      = (const float*)d_in[2];  // [4][512][512]
    const float* Wk      = (const float*)d_in[3];  // [4][960][960]
    const float* Wv      = (const float*)d_in[4];  // [4][960][960]
    const float* Wo      = (const float*)d_in[5];  // [512][512]
    float* out = (float*)d_out;

    char* ws = (char*)d_ws;
    unsigned short* embT     = (unsigned short*)(ws);              // [b][512][4096]
    unsigned short* emb_allT = (unsigned short*)(ws + 16777216);   // [b][1024][4096]
    unsigned short* emb_allB = (unsigned short*)(ws + 50331648);   // [b][4096][960]
    unsigned short* WqB      = (unsigned short*)(ws + 81788928);   // [h][512][512]
    unsigned short* WkB      = (unsigned short*)(ws + 83886080);   // [h][1024][960]
    unsigned short* WvT      = (unsigned short*)(ws + 91750400);   // [h][1024][960]
    unsigned short* WoB      = (unsigned short*)(ws + 99614720);   // [512][512]
    unsigned short* GT       = (unsigned short*)(ws + 100139008);  // [b][1024][512]
    unsigned short* probs    = (unsigned short*)(ws + 104333312);  // [z][512][1024]
    float2* sc_part          = (float2*)(ws + 121110528);          // [16][32]
    unsigned short* partK    = (unsigned short*)(ws + 134217728);  // 16 MB bf16

    // region reuse (sequential liveness)
    unsigned short* S1  = embT;                             // embT dead after splitk
    unsigned short* SC  = emb_allT;                         // emb_allT dead after splitk
    unsigned short* UT  = (unsigned short*)(ws + 33554432); // 2nd half of emb_allT region
    unsigned short* UbT = GT;                               // GT dead after step 2
    unsigned short* W2  = embT;                             // S1 dead after step 3

    // ---- 0. all preps, one launch ----
    prep_all<<<12224, 256, 0, stream>>>(emb, emb_all, Wq, Wk, Wv, Wo,
                                        embT, emb_allT, emb_allB, WqB, WkB, WvT, WoB);

    // ---- 1. split-K (z = b*4+sp): partK[z] = emb_allT chunk x embT chunk^T ----
    gemm_bt<unsigned short, false><<<dim3(4, 8, 16), 256, 0, stream>>>(
        emb_allT, embT, partK, nullptr, 1024, 4096, 4096, 512,
        1024L*4096, 1024, 512L*4096, 1024, 1024L*512, 4, 1.f);
    reduce_gt<<<1024, 256, 0, stream>>>(partK, GT);

    // ---- 2. S1[b,h] = Wq[h] x GT[b]^T  (M=512, N=1024, K=512) ----
    gemm_bt<unsigned short, false><<<dim3(8, 4, 16), 256, 0, stream>>>(
        WqB, GT, S1, nullptr, 512, 512, 512, 1024,
        0, 512L*512, 1024L*512, 0, 512L*1024, 4, 1.f);

    // ---- 3. SC[z] = S1[z] x WkB[h]^T (bf16 out) + fused stats partials ----
    gemm_bt<unsigned short, true><<<dim3(8, 4, 16), 256, 0, stream>>>(
        S1, WkB, SC, sc_part, 960, 1024, 960, 1024,
        4L*512*1024, 512L*1024, 0, 1024L*960, 512L*1024, 4, 1.f);

    // ---- 4. fused instance-norm + softmax (wave-per-row) ----
    norm_softmax<<<2048, 256, 0, stream>>>(SC, sc_part, probs);

    // ---- 5. UT[z] = WvT[h] x probs[z]^T * 0.25  (M=1024, N=512, K=960) ----
    gemm_bt<unsigned short, false><<<dim3(4, 8, 16), 256, 0, stream>>>(
        WvT, probs, UT, nullptr, 960, 960, 1024, 512,
        0, 1024L*960, 4L*512*1024, 512L*1024, 1024L*512, 4, 0.25f);

    // ---- 6. UbT[b] = sum_h UT[b,h] ----
    mean_heads<<<1024, 256, 0, stream>>>(UT, UbT);

    // ---- 7. W2[b] = WoB x UbT[b]^T  (M=512, N=1024, K=512) ----
    gemm_bt<unsigned short, false><<<dim3(8, 4, 4), 256, 0, stream>>>(
        WoB, UbT, W2, nullptr, 512, 512, 512, 1024,
        0, 0, 1024L*512, 0, 512L*1024, 1, 1.f);

    // ---- 8. out[b] = emb_allB[b] x W2[b]^T  (M=4096, N=512, K=960) ----
    gemm_bt<float, false><<<dim3(4, 32, 4), 256, 0, stream>>>(
        emb_allB, W2, out, nullptr, 960, 960, 1024, 512,
        4096L*960, 0, 512L*1024, 0, 4096L*512, 1, 1.f);
}

// Round 8
// 200.609 us; speedup vs baseline: 12.6122x; 1.0431x over previous
//
#include <hip/hip_runtime.h>
#include <math.h>

typedef __attribute__((ext_vector_type(8))) short short8;
typedef __attribute__((ext_vector_type(4))) float f32x4;

__device__ __forceinline__ unsigned short f2bf(float f) {
    unsigned int u; __builtin_memcpy(&u, &f, 4);
    unsigned int r = (u + 0x7FFFu + ((u >> 16) & 1u)) >> 16;
    return (unsigned short)r;
}
__device__ __forceinline__ float bf2f(unsigned short h) {
    unsigned int u = ((unsigned int)h) << 16;
    float f; __builtin_memcpy(&f, &u, 4); return f;
}
__device__ __forceinline__ void gl2lds16(const unsigned short* g, unsigned short* l) {
    __builtin_amdgcn_global_load_lds(
        (const __attribute__((address_space(1))) unsigned int*)g,
        (__attribute__((address_space(3))) unsigned int*)l, 16, 0, 0);
}

// ---------------------------------------------------------------------------
// bf16 MFMA GEMM, double-buffered 2-phase pipeline, 8 waves (512 threads).
// C[m][n] = alpha * sum_k A[m,k]*B[n,k]; tile 128x128, BK=32.
// Wave w (wr=w>>2, wc=w&3) owns a 64x32 output sub-tile: acc[4][2].
// Each wave stages one A-chunk and one B-chunk (16 rows x 32 k = 1 KiB).
// 2 blocks/CU -> 16 waves/CU = 4 waves/SIMD (max occupancy).
// STATS: also emit per-block (sum, sumsq) fp32 partials for InstanceNorm.
// ---------------------------------------------------------------------------
template<typename OutT, bool STATS>
__global__ __launch_bounds__(512)
void gemm_bt(const unsigned short* __restrict__ A, const unsigned short* __restrict__ B,
             OutT* __restrict__ C, float2* __restrict__ sp_out,
             int K, long lda, long ldb, long ldc,
             long sa_bb, long sa_bh, long sb_bb, long sb_bh, long sc_z,
             int H, float alpha)
{
    __shared__ unsigned short As[2][128 * 32];
    __shared__ unsigned short Bs[2][128 * 32];

    const int z = blockIdx.z;
    const int bb = z / H, hh = z - bb * H;
    A += (long)bb * sa_bb + (long)hh * sa_bh;
    B += (long)bb * sb_bb + (long)hh * sb_bh;
    C += (long)z * sc_z;

    const int tid  = threadIdx.x;
    const int lane = tid & 63;
    const int wave = tid >> 6;           // 0..7
    const int wr = wave >> 2, wc = wave & 3;

    const long m0 = (long)blockIdx.y * 128;
    const long n0 = (long)blockIdx.x * 128;

    // staging: wave w stages A-chunk w and B-chunk w (16 rows x 32 k each)
    const int lrow = lane >> 2;          // 0..15
    const int lcol = (lane & 3) * 8;     // k-elem offset
    const unsigned short* ga = A + (m0 + wave * 16 + lrow) * lda + lcol;
    const unsigned short* gb = B + (n0 + wave * 16 + lrow) * ldb + lcol;

    auto stg = [&](int buf, long koff) {
        gl2lds16(ga + koff, &As[buf][wave * 512]);
        gl2lds16(gb + koff, &Bs[buf][wave * 512]);
    };

    const int fr = lane & 15;
    const int fk = (lane >> 4) * 8;

    f32x4 acc[4][2];
    const f32x4 zero4 = {0.f, 0.f, 0.f, 0.f};
    #pragma unroll
    for (int i = 0; i < 4; ++i)
        #pragma unroll
        for (int j = 0; j < 2; ++j) acc[i][j] = zero4;

    stg(0, 0);
    __syncthreads();

    int cur = 0;
    for (long k0 = 0; k0 < K; k0 += 32) {
        if (k0 + 32 < K) stg(cur ^ 1, k0 + 32);

        const unsigned short* ra = &As[cur][(wr * 64 + fr) * 32 + fk];
        const unsigned short* rb = &Bs[cur][(wc * 32 + fr) * 32 + fk];
        short8 af[4], bfr[2];
        #pragma unroll
        for (int i = 0; i < 4; ++i) af[i]  = *(const short8*)(ra + i * 512);
        #pragma unroll
        for (int j = 0; j < 2; ++j) bfr[j] = *(const short8*)(rb + j * 512);
        #pragma unroll
        for (int i = 0; i < 4; ++i)
            #pragma unroll
            for (int j = 0; j < 2; ++j)
                acc[i][j] = __builtin_amdgcn_mfma_f32_16x16x32_bf16(af[i], bfr[j], acc[i][j], 0, 0, 0);

        __syncthreads();
        cur ^= 1;
    }

    float s = 0.f, s2 = 0.f;
    const int orow = (lane >> 4) * 4;
    #pragma unroll
    for (int i = 0; i < 4; ++i) {
        const long rbase = m0 + wr * 64 + i * 16 + orow;
        #pragma unroll
        for (int j = 0; j < 2; ++j) {
            const long cidx = n0 + wc * 32 + j * 16 + fr;
            f32x4 v = acc[i][j];
            #pragma unroll
            for (int q = 0; q < 4; ++q) {
                float val = alpha * v[q];
                if constexpr (STATS) { s += val; s2 += val * val; }
                if constexpr (sizeof(OutT) == 4) C[(rbase + q) * ldc + cidx] = val;
                else                             C[(rbase + q) * ldc + cidx] = f2bf(val);
            }
        }
    }

    if constexpr (STATS) {
        float* red = (float*)&As[0][0];
        red[tid] = s; red[512 + tid] = s2;
        __syncthreads();
        for (int off = 256; off > 0; off >>= 1) {
            if (tid < off) { red[tid] += red[tid + off]; red[512 + tid] += red[512 + tid + off]; }
            __syncthreads();
        }
        if (tid == 0)
            sp_out[(long)z * 32 + blockIdx.y * gridDim.x + blockIdx.x] =
                make_float2(red[0], red[512]);
    }
}

// ---------------------------------------------------------------------------
// 64x64 vectorized transpose-cast worker (float4 read, ushort4 writes).
// ---------------------------------------------------------------------------
__device__ __forceinline__
void tc64_impl(const float* __restrict__ in, unsigned short* __restrict__ outT,
               unsigned short* __restrict__ outB, int R, int Cin,
               int bx, int by, bool dual, float (*t)[65])
{
    const int r0 = bx * 64, c0 = by * 64;
    const int tid = threadIdx.x;
    const int rr  = tid >> 4;
    const int cc4 = (tid & 15) * 4;
    const bool real = (c0 + cc4) < Cin;

    #pragma unroll
    for (int i = 0; i < 4; ++i) {
        const int r = rr + i * 16;
        float4 v = make_float4(0.f, 0.f, 0.f, 0.f);
        if (real) v = *(const float4*)(in + (long)(r0 + r) * Cin + c0 + cc4);
        t[r][cc4] = v.x; t[r][cc4 + 1] = v.y; t[r][cc4 + 2] = v.z; t[r][cc4 + 3] = v.w;
        if (dual && real) {
            ushort4 o;
            o.x = f2bf(v.x); o.y = f2bf(v.y); o.z = f2bf(v.z); o.w = f2bf(v.w);
            *(ushort4*)(outB + (long)(r0 + r) * Cin + c0 + cc4) = o;
        }
    }
    __syncthreads();
    #pragma unroll
    for (int i = 0; i < 4; ++i) {
        const int c = rr + i * 16;
        ushort4 o;
        o.x = f2bf(t[cc4 + 0][c]);
        o.y = f2bf(t[cc4 + 1][c]);
        o.z = f2bf(t[cc4 + 2][c]);
        o.w = f2bf(t[cc4 + 3][c]);
        *(ushort4*)(outT + (long)(c0 + c) * R + r0 + cc4) = o;
    }
}

// ---------------------------------------------------------------------------
// ALL preps in one launch (block-range segmented).
// ---------------------------------------------------------------------------
__global__ __launch_bounds__(256)
void prep_all(const float* __restrict__ emb, const float* __restrict__ emb_all,
              const float* __restrict__ Wq, const float* __restrict__ Wk,
              const float* __restrict__ Wv, const float* __restrict__ Wo,
              unsigned short* __restrict__ embT, unsigned short* __restrict__ emb_allT,
              unsigned short* __restrict__ emb_allB, unsigned short* __restrict__ WqB,
              unsigned short* __restrict__ WkB, unsigned short* __restrict__ WvT,
              unsigned short* __restrict__ WoB)
{
    __shared__ float t[64][65];
    int bid = blockIdx.x;
    if (bid < 4096) {
        const int z = bid >> 10, r2 = bid & 1023, by = r2 >> 6, bx = r2 & 63;
        tc64_impl(emb_all + (long)z * 4096 * 960, emb_allT + (long)z * 1024 * 4096,
                  emb_allB + (long)z * 4096 * 960, 4096, 960, bx, by, true, t);
        return;
    }
    bid -= 4096;
    if (bid < 2048) {
        const int z = bid >> 9, r2 = bid & 511, by = r2 >> 6, bx = r2 & 63;
        tc64_impl(emb + (long)z * 4096 * 512, embT + (long)z * 512 * 4096,
                  nullptr, 4096, 512, bx, by, false, t);
        return;
    }
    bid -= 2048;
    if (bid < 960) {
        const int z = bid / 240, r2 = bid % 240, by = r2 / 15, bx = r2 % 15;
        tc64_impl(Wv + (long)z * 960 * 960, WvT + (long)z * 1024 * 960,
                  nullptr, 960, 960, bx, by, false, t);
        return;
    }
    bid -= 960;
    long q = (long)bid * 256 + threadIdx.x;
    if (q < 983040) {                       // WkB
        long e = q * 4;
        long h = e / 983040L; long r2 = e - h * 983040L;
        long r = r2 / 960;    long c = r2 - r * 960;
        ushort4 o = {0, 0, 0, 0};
        if (r < 960) {
            float4 v = *(const float4*)(Wk + (h * 960 + r) * 960 + c);
            o.x = f2bf(v.x); o.y = f2bf(v.y); o.z = f2bf(v.z); o.w = f2bf(v.w);
        }
        *(ushort4*)(WkB + e) = o;
        return;
    }
    q -= 983040;
    if (q < 262144) {                       // WqB
        long e = q * 4;
        float4 v = *(const float4*)(Wq + e);
        ushort4 o; o.x = f2bf(v.x); o.y = f2bf(v.y); o.z = f2bf(v.z); o.w = f2bf(v.w);
        *(ushort4*)(WqB + e) = o;
        return;
    }
    q -= 262144;
    if (q < 65536) {                        // WoB
        long e = q * 4;
        float4 v = *(const float4*)(Wo + e);
        ushort4 o; o.x = f2bf(v.x); o.y = f2bf(v.y); o.z = f2bf(v.z); o.w = f2bf(v.w);
        *(ushort4*)(WoB + e) = o;
    }
}

// GT[b][r] = f2bf(sum_sp bf16 partK[b][sp][r]); 8 elems/thread, 1024 blocks.
__global__ __launch_bounds__(256)
void reduce_gt(const unsigned short* __restrict__ part, unsigned short* __restrict__ GT)
{
    long i = ((long)blockIdx.x * 256 + threadIdx.x) * 8;
    long b = i >> 19, r = i & 524287;
    const unsigned short* p = part + b * 4 * 524288 + r;
    const short8 v0 = *(const short8*)(p);
    const short8 v1 = *(const short8*)(p + 524288);
    const short8 v2 = *(const short8*)(p + 2 * 524288);
    const short8 v3 = *(const short8*)(p + 3 * 524288);
    short8 o;
    #pragma unroll
    for (int k = 0; k < 8; ++k) {
        float s = bf2f((unsigned short)v0[k]) + bf2f((unsigned short)v1[k])
                + bf2f((unsigned short)v2[k]) + bf2f((unsigned short)v3[k]);
        o[k] = (short)f2bf(s);
    }
    *(short8*)(GT + i) = o;
}

// ---------------------------------------------------------------------------
// norm + softmax, one WAVE per row (shfl-only reductions).
// ---------------------------------------------------------------------------
__global__ __launch_bounds__(256)
void norm_softmax(const unsigned short* __restrict__ SC, const float2* __restrict__ part,
                  unsigned short* __restrict__ probs)
{
    const int lane = threadIdx.x & 63;
    const int wave = threadIdx.x >> 6;
    const long row = (long)blockIdx.x * 4 + wave;
    const int z = (int)(row >> 9);

    float2 pv = part[z * 32 + (lane & 31)];
    float a = pv.x, b = pv.y;
    #pragma unroll
    for (int off = 1; off < 32; off <<= 1) {
        a += __shfl_xor(a, off);
        b += __shfl_xor(b, off);
    }
    const float ninv = 1.f / (512.f * 960.f);
    const float mean = a * ninv;
    const float rstd = rsqrtf(b * ninv - mean * mean + 960.f * 1e-5f);

    const unsigned short* p = SC + row * 1024 + lane * 16;
    const bool act = lane < 60;
    float x[16];
    {
        const short8 w0 = *(const short8*)(p);
        const short8 w1 = *(const short8*)(p + 8);
        #pragma unroll
        for (int k = 0; k < 8; ++k) {
            x[k]     = (bf2f((unsigned short)w0[k]) - mean) * rstd;
            x[k + 8] = (bf2f((unsigned short)w1[k]) - mean) * rstd;
        }
    }
    float mx = -1e30f;
    if (act) {
        #pragma unroll
        for (int k = 0; k < 16; ++k) mx = fmaxf(mx, x[k]);
    }
    #pragma unroll
    for (int off = 1; off < 64; off <<= 1) mx = fmaxf(mx, __shfl_xor(mx, off));

    float s = 0.f;
    if (act) {
        #pragma unroll
        for (int k = 0; k < 16; ++k) { x[k] = __expf(x[k] - mx); s += x[k]; }
    }
    #pragma unroll
    for (int off = 1; off < 64; off <<= 1) s += __shfl_xor(s, off);
    const float inv = 1.f / s;

    unsigned short* o = probs + row * 1024 + lane * 16;
    short8 o0 = {0,0,0,0,0,0,0,0}, o1 = {0,0,0,0,0,0,0,0};
    if (act) {
        #pragma unroll
        for (int k = 0; k < 8; ++k) {
            o0[k] = (short)f2bf(x[k] * inv);
            o1[k] = (short)f2bf(x[k + 8] * inv);
        }
    }
    *(short8*)(o)     = o0;
    *(short8*)(o + 8) = o1;
}

// ---------------------------------------------------------------------------
// UbarT[b] = sum_h UT[b*4+h]; 8 elems/thread.
// ---------------------------------------------------------------------------
__global__ __launch_bounds__(256)
void mean_heads(const unsigned short* __restrict__ UT, unsigned short* __restrict__ Ub)
{
    const long per = 1024L * 512;
    long e = ((long)blockIdx.x * 256 + threadIdx.x) * 8;
    long b = e / per; long r = e - b * per;
    const short8 v0 = *(const short8*)(UT + (b * 4 + 0) * per + r);
    const short8 v1 = *(const short8*)(UT + (b * 4 + 1) * per + r);
    const short8 v2 = *(const short8*)(UT + (b * 4 + 2) * per + r);
    const short8 v3 = *(const short8*)(UT + (b * 4 + 3) * per + r);
    short8 o;
    #pragma unroll
    for (int k = 0; k < 8; ++k) {
        float s = bf2f((unsigned short)v0[k]) + bf2f((unsigned short)v1[k])
                + bf2f((unsigned short)v2[k]) + bf2f((unsigned short)v3[k]);
        o[k] = (short)f2bf(s);
    }
    *(short8*)(Ub + b * per + r) = o;
}

// ---------------------------------------------------------------------------
extern "C" void kernel_launch(void* const* d_in, const int* in_sizes, int n_in,
                              void* d_out, int out_size, void* d_ws, size_t ws_size,
                              hipStream_t stream)
{
    const float* emb     = (const float*)d_in[0];  // [4][4096][512]
    const float* emb_all = (const float*)d_in[1];  // [4][4096][960]
    const float* Wq      = (const float*)d_in[2];  // [4][512][512]
    const float* Wk      = (const float*)d_in[3];  // [4][960][960]
    const float* Wv      = (const float*)d_in[4];  // [4][960][960]
    const float* Wo      = (const float*)d_in[5];  // [512][512]
    float* out = (float*)d_out;

    char* ws = (char*)d_ws;
    unsigned short* embT     = (unsigned short*)(ws);              // [b][512][4096]
    unsigned short* emb_allT = (unsigned short*)(ws + 16777216);   // [b][1024][4096]
    unsigned short* emb_allB = (unsigned short*)(ws + 50331648);   // [b][4096][960]
    unsigned short* WqB      = (unsigned short*)(ws + 81788928);   // [h][512][512]
    unsigned short* WkB      = (unsigned short*)(ws + 83886080);   // [h][1024][960]
    unsigned short* WvT      = (unsigned short*)(ws + 91750400);   // [h][1024][960]
    unsigned short* WoB      = (unsigned short*)(ws + 99614720);   // [512][512]
    unsigned short* GT       = (unsigned short*)(ws + 100139008);  // [b][1024][512]
    unsigned short* probs    = (unsigned short*)(ws + 104333312);  // [z][512][1024]
    float2* sc_part          = (float2*)(ws + 121110528);          // [16][32]
    unsigned short* partK    = (unsigned short*)(ws + 134217728);  // 16 MB bf16

    // region reuse (sequential liveness)
    unsigned short* S1  = embT;
    unsigned short* SC  = emb_allT;
    unsigned short* UT  = (unsigned short*)(ws + 33554432);
    unsigned short* UbT = GT;
    unsigned short* W2  = embT;

    // ---- 0. all preps, one launch ----
    prep_all<<<12224, 256, 0, stream>>>(emb, emb_all, Wq, Wk, Wv, Wo,
                                        embT, emb_allT, emb_allB, WqB, WkB, WvT, WoB);

    // ---- 1. split-K (z = b*4+sp): partK[z] = emb_allT chunk x embT chunk^T ----
    gemm_bt<unsigned short, false><<<dim3(4, 8, 16), 512, 0, stream>>>(
        emb_allT, embT, partK, nullptr, 1024, 4096, 4096, 512,
        1024L*4096, 1024, 512L*4096, 1024, 1024L*512, 4, 1.f);
    reduce_gt<<<1024, 256, 0, stream>>>(partK, GT);

    // ---- 2. S1[b,h] = Wq[h] x GT[b]^T  (M=512, N=1024, K=512) ----
    gemm_bt<unsigned short, false><<<dim3(8, 4, 16), 512, 0, stream>>>(
        WqB, GT, S1, nullptr, 512, 512, 512, 1024,
        0, 512L*512, 1024L*512, 0, 512L*1024, 4, 1.f);

    // ---- 3. SC[z] = S1[z] x WkB[h]^T (bf16 out) + fused stats partials ----
    gemm_bt<unsigned short, true><<<dim3(8, 4, 16), 512, 0, stream>>>(
        S1, WkB, SC, sc_part, 960, 1024, 960, 1024,
        4L*512*1024, 512L*1024, 0, 1024L*960, 512L*1024, 4, 1.f);

    // ---- 4. fused instance-norm + softmax (wave-per-row) ----
    norm_softmax<<<2048, 256, 0, stream>>>(SC, sc_part, probs);

    // ---- 5. UT[z] = WvT[h] x probs[z]^T * 0.25  (M=1024, N=512, K=960) ----
    gemm_bt<unsigned short, false><<<dim3(4, 8, 16), 512, 0, stream>>>(
        WvT, probs, UT, nullptr, 960, 960, 1024, 512,
        0, 1024L*960, 4L*512*1024, 512L*1024, 1024L*512, 4, 0.25f);

    // ---- 6. UbT[b] = sum_h UT[b,h] ----
    mean_heads<<<1024, 256, 0, stream>>>(UT, UbT);

    // ---- 7. W2[b] = WoB x UbT[b]^T  (M=512, N=1024, K=512) ----
    gemm_bt<unsigned short, false><<<dim3(8, 4, 4), 512, 0, stream>>>(
        WoB, UbT, W2, nullptr, 512, 512, 512, 1024,
        0, 0, 1024L*512, 0, 512L*1024, 1, 1.f);

    // ---- 8. out[b] = emb_allB[b] x W2[b]^T  (M=4096, N=512, K=960) ----
    gemm_bt<float, false><<<dim3(4, 32, 4), 512, 0, stream>>>(
        emb_allB, W2, out, nullptr, 960, 960, 1024, 512,
        4096L*960, 0, 512L*1024, 0, 4096L*512, 1, 1.f);
}

// Round 9
// 200.240 us; speedup vs baseline: 12.6354x; 1.0018x over previous
//
#include <hip/hip_runtime.h>
#include <math.h>

typedef __attribute__((ext_vector_type(8))) short short8;
typedef __attribute__((ext_vector_type(4))) float f32x4;

__device__ __forceinline__ unsigned short f2bf(float f) {
    unsigned int u; __builtin_memcpy(&u, &f, 4);
    unsigned int r = (u + 0x7FFFu + ((u >> 16) & 1u)) >> 16;
    return (unsigned short)r;
}
__device__ __forceinline__ float bf2f(unsigned short h) {
    unsigned int u = ((unsigned int)h) << 16;
    float f; __builtin_memcpy(&f, &u, 4); return f;
}
__device__ __forceinline__ void gl2lds16(const unsigned short* g, unsigned short* l) {
    __builtin_amdgcn_global_load_lds(
        (const __attribute__((address_space(1))) unsigned int*)g,
        (__attribute__((address_space(3))) unsigned int*)l, 16, 0, 0);
}

// ---------------------------------------------------------------------------
// bf16 MFMA GEMM, double-buffered 2-phase pipeline, 8 waves (512 threads).
// C[m][n] = alpha * sum_k A[m,k]*B[n,k]; tile 128x128, BK=32.
// Wave w (wr=w>>2, wc=w&3) owns a 64x32 output sub-tile: acc[4][2].
// STATS: also emit per-block (sum, sumsq) fp32 partials for InstanceNorm.
// ---------------------------------------------------------------------------
template<typename OutT, bool STATS>
__global__ __launch_bounds__(512)
void gemm_bt(const unsigned short* __restrict__ A, const unsigned short* __restrict__ B,
             OutT* __restrict__ C, float2* __restrict__ sp_out,
             int K, long lda, long ldb, long ldc,
             long sa_bb, long sa_bh, long sb_bb, long sb_bh, long sc_z,
             int H, float alpha)
{
    __shared__ unsigned short As[2][128 * 32];
    __shared__ unsigned short Bs[2][128 * 32];

    const int z = blockIdx.z;
    const int bb = z / H, hh = z - bb * H;
    A += (long)bb * sa_bb + (long)hh * sa_bh;
    B += (long)bb * sb_bb + (long)hh * sb_bh;
    C += (long)z * sc_z;

    const int tid  = threadIdx.x;
    const int lane = tid & 63;
    const int wave = tid >> 6;           // 0..7
    const int wr = wave >> 2, wc = wave & 3;

    const long m0 = (long)blockIdx.y * 128;
    const long n0 = (long)blockIdx.x * 128;

    const int lrow = lane >> 2;          // 0..15
    const int lcol = (lane & 3) * 8;     // k-elem offset
    const unsigned short* ga = A + (m0 + wave * 16 + lrow) * lda + lcol;
    const unsigned short* gb = B + (n0 + wave * 16 + lrow) * ldb + lcol;

    auto stg = [&](int buf, long koff) {
        gl2lds16(ga + koff, &As[buf][wave * 512]);
        gl2lds16(gb + koff, &Bs[buf][wave * 512]);
    };

    const int fr = lane & 15;
    const int fk = (lane >> 4) * 8;

    f32x4 acc[4][2];
    const f32x4 zero4 = {0.f, 0.f, 0.f, 0.f};
    #pragma unroll
    for (int i = 0; i < 4; ++i)
        #pragma unroll
        for (int j = 0; j < 2; ++j) acc[i][j] = zero4;

    stg(0, 0);
    __syncthreads();

    int cur = 0;
    for (long k0 = 0; k0 < K; k0 += 32) {
        if (k0 + 32 < K) stg(cur ^ 1, k0 + 32);

        const unsigned short* ra = &As[cur][(wr * 64 + fr) * 32 + fk];
        const unsigned short* rb = &Bs[cur][(wc * 32 + fr) * 32 + fk];
        short8 af[4], bfr[2];
        #pragma unroll
        for (int i = 0; i < 4; ++i) af[i]  = *(const short8*)(ra + i * 512);
        #pragma unroll
        for (int j = 0; j < 2; ++j) bfr[j] = *(const short8*)(rb + j * 512);
        #pragma unroll
        for (int i = 0; i < 4; ++i)
            #pragma unroll
            for (int j = 0; j < 2; ++j)
                acc[i][j] = __builtin_amdgcn_mfma_f32_16x16x32_bf16(af[i], bfr[j], acc[i][j], 0, 0, 0);

        __syncthreads();
        cur ^= 1;
    }

    float s = 0.f, s2 = 0.f;
    const int orow = (lane >> 4) * 4;
    #pragma unroll
    for (int i = 0; i < 4; ++i) {
        const long rbase = m0 + wr * 64 + i * 16 + orow;
        #pragma unroll
        for (int j = 0; j < 2; ++j) {
            const long cidx = n0 + wc * 32 + j * 16 + fr;
            f32x4 v = acc[i][j];
            #pragma unroll
            for (int q = 0; q < 4; ++q) {
                float val = alpha * v[q];
                if constexpr (STATS) { s += val; s2 += val * val; }
                if constexpr (sizeof(OutT) == 4) C[(rbase + q) * ldc + cidx] = val;
                else                             C[(rbase + q) * ldc + cidx] = f2bf(val);
            }
        }
    }

    if constexpr (STATS) {
        float* red = (float*)&As[0][0];
        red[tid] = s; red[512 + tid] = s2;
        __syncthreads();
        for (int off = 256; off > 0; off >>= 1) {
            if (tid < off) { red[tid] += red[tid + off]; red[512 + tid] += red[512 + tid + off]; }
            __syncthreads();
        }
        if (tid == 0)
            sp_out[(long)z * 32 + blockIdx.y * gridDim.x + blockIdx.x] =
                make_float2(red[0], red[512]);
    }
}

// ---------------------------------------------------------------------------
// 64x64 transpose-cast worker, LDS-vectorized:
//   cast f32->bf16 in registers, ds_write_b64 (ushort4) into [64][68] tile,
//   paired ds_read_b32 (2 cols/read), each thread emits 2 transposed ushort4
//   rows per group. LDS ops/thread: 4 writes + 8 reads (was 32 scalar).
// ---------------------------------------------------------------------------
__device__ __forceinline__
void tc64_impl(const float* __restrict__ in, unsigned short* __restrict__ outT,
               unsigned short* __restrict__ outB, int R, int Cin,
               int bx, int by, bool dual, unsigned short (*t)[68])
{
    const int r0 = bx * 64, c0 = by * 64;
    const int tid = threadIdx.x;
    const int rr  = tid >> 4;          // 0..15
    const int cc4 = (tid & 15) * 4;    // 0..60
    const bool real = (c0 + cc4) < Cin;

    #pragma unroll
    for (int i = 0; i < 4; ++i) {
        const int r = rr + i * 16;
        float4 v = make_float4(0.f, 0.f, 0.f, 0.f);
        if (real) v = *(const float4*)(in + (long)(r0 + r) * Cin + c0 + cc4);
        ushort4 o;
        o.x = f2bf(v.x); o.y = f2bf(v.y); o.z = f2bf(v.z); o.w = f2bf(v.w);
        *(ushort4*)&t[r][cc4] = o;                       // ds_write_b64, conflict-free
        if (dual && real)
            *(ushort4*)(outB + (long)(r0 + r) * Cin + c0 + cc4) = o;
    }
    __syncthreads();
    #pragma unroll
    for (int i = 0; i < 2; ++i) {
        const int p = rr + i * 16;      // 0..31 -> out-row pair (2p, 2p+1)
        const int c = 2 * p;
        ushort2 a0 = *(const ushort2*)&t[cc4 + 0][c];    // ds_read_b32
        ushort2 a1 = *(const ushort2*)&t[cc4 + 1][c];
        ushort2 a2 = *(const ushort2*)&t[cc4 + 2][c];
        ushort2 a3 = *(const ushort2*)&t[cc4 + 3][c];
        ushort4 w0; w0.x = a0.x; w0.y = a1.x; w0.z = a2.x; w0.w = a3.x;
        ushort4 w1; w1.x = a0.y; w1.y = a1.y; w1.z = a2.y; w1.w = a3.y;
        *(ushort4*)(outT + (long)(c0 + c) * R + r0 + cc4)     = w0;
        *(ushort4*)(outT + (long)(c0 + c + 1) * R + r0 + cc4) = w1;
    }
}

// ---------------------------------------------------------------------------
// ALL preps in one launch (block-range segmented).
// ---------------------------------------------------------------------------
__global__ __launch_bounds__(256)
void prep_all(const float* __restrict__ emb, const float* __restrict__ emb_all,
              const float* __restrict__ Wq, const float* __restrict__ Wk,
              const float* __restrict__ Wv, const float* __restrict__ Wo,
              unsigned short* __restrict__ embT, unsigned short* __restrict__ emb_allT,
              unsigned short* __restrict__ emb_allB, unsigned short* __restrict__ WqB,
              unsigned short* __restrict__ WkB, unsigned short* __restrict__ WvT,
              unsigned short* __restrict__ WoB)
{
    __shared__ unsigned short t[64][68];
    int bid = blockIdx.x;
    if (bid < 4096) {
        const int z = bid >> 10, r2 = bid & 1023, by = r2 >> 6, bx = r2 & 63;
        tc64_impl(emb_all + (long)z * 4096 * 960, emb_allT + (long)z * 1024 * 4096,
                  emb_allB + (long)z * 4096 * 960, 4096, 960, bx, by, true, t);
        return;
    }
    bid -= 4096;
    if (bid < 2048) {
        const int z = bid >> 9, r2 = bid & 511, by = r2 >> 6, bx = r2 & 63;
        tc64_impl(emb + (long)z * 4096 * 512, embT + (long)z * 512 * 4096,
                  nullptr, 4096, 512, bx, by, false, t);
        return;
    }
    bid -= 2048;
    if (bid < 960) {
        const int z = bid / 240, r2 = bid % 240, by = r2 / 15, bx = r2 % 15;
        tc64_impl(Wv + (long)z * 960 * 960, WvT + (long)z * 1024 * 960,
                  nullptr, 960, 960, bx, by, false, t);
        return;
    }
    bid -= 960;
    long q = (long)bid * 256 + threadIdx.x;
    if (q < 983040) {                       // WkB
        long e = q * 4;
        long h = e / 983040L; long r2 = e - h * 983040L;
        long r = r2 / 960;    long c = r2 - r * 960;
        ushort4 o = {0, 0, 0, 0};
        if (r < 960) {
            float4 v = *(const float4*)(Wk + (h * 960 + r) * 960 + c);
            o.x = f2bf(v.x); o.y = f2bf(v.y); o.z = f2bf(v.z); o.w = f2bf(v.w);
        }
        *(ushort4*)(WkB + e) = o;
        return;
    }
    q -= 983040;
    if (q < 262144) {                       // WqB
        long e = q * 4;
        float4 v = *(const float4*)(Wq + e);
        ushort4 o; o.x = f2bf(v.x); o.y = f2bf(v.y); o.z = f2bf(v.z); o.w = f2bf(v.w);
        *(ushort4*)(WqB + e) = o;
        return;
    }
    q -= 262144;
    if (q < 65536) {                        // WoB
        long e = q * 4;
        float4 v = *(const float4*)(Wo + e);
        ushort4 o; o.x = f2bf(v.x); o.y = f2bf(v.y); o.z = f2bf(v.z); o.w = f2bf(v.w);
        *(ushort4*)(WoB + e) = o;
    }
}

// GT[b][r] = f2bf(sum_sp bf16 partK[b][sp][r]); 8 elems/thread, 1024 blocks.
__global__ __launch_bounds__(256)
void reduce_gt(const unsigned short* __restrict__ part, unsigned short* __restrict__ GT)
{
    long i = ((long)blockIdx.x * 256 + threadIdx.x) * 8;
    long b = i >> 19, r = i & 524287;
    const unsigned short* p = part + b * 4 * 524288 + r;
    const short8 v0 = *(const short8*)(p);
    const short8 v1 = *(const short8*)(p + 524288);
    const short8 v2 = *(const short8*)(p + 2 * 524288);
    const short8 v3 = *(const short8*)(p + 3 * 524288);
    short8 o;
    #pragma unroll
    for (int k = 0; k < 8; ++k) {
        float s = bf2f((unsigned short)v0[k]) + bf2f((unsigned short)v1[k])
                + bf2f((unsigned short)v2[k]) + bf2f((unsigned short)v3[k]);
        o[k] = (short)f2bf(s);
    }
    *(short8*)(GT + i) = o;
}

// ---------------------------------------------------------------------------
// norm + softmax, one WAVE per row (shfl-only reductions).
// ---------------------------------------------------------------------------
__global__ __launch_bounds__(256)
void norm_softmax(const unsigned short* __restrict__ SC, const float2* __restrict__ part,
                  unsigned short* __restrict__ probs)
{
    const int lane = threadIdx.x & 63;
    const int wave = threadIdx.x >> 6;
    const long row = (long)blockIdx.x * 4 + wave;
    const int z = (int)(row >> 9);

    float2 pv = part[z * 32 + (lane & 31)];
    float a = pv.x, b = pv.y;
    #pragma unroll
    for (int off = 1; off < 32; off <<= 1) {
        a += __shfl_xor(a, off);
        b += __shfl_xor(b, off);
    }
    const float ninv = 1.f / (512.f * 960.f);
    const float mean = a * ninv;
    const float rstd = rsqrtf(b * ninv - mean * mean + 960.f * 1e-5f);

    const unsigned short* p = SC + row * 1024 + lane * 16;
    const bool act = lane < 60;
    float x[16];
    {
        const short8 w0 = *(const short8*)(p);
        const short8 w1 = *(const short8*)(p + 8);
        #pragma unroll
        for (int k = 0; k < 8; ++k) {
            x[k]     = (bf2f((unsigned short)w0[k]) - mean) * rstd;
            x[k + 8] = (bf2f((unsigned short)w1[k]) - mean) * rstd;
        }
    }
    float mx = -1e30f;
    if (act) {
        #pragma unroll
        for (int k = 0; k < 16; ++k) mx = fmaxf(mx, x[k]);
    }
    #pragma unroll
    for (int off = 1; off < 64; off <<= 1) mx = fmaxf(mx, __shfl_xor(mx, off));

    float s = 0.f;
    if (act) {
        #pragma unroll
        for (int k = 0; k < 16; ++k) { x[k] = __expf(x[k] - mx); s += x[k]; }
    }
    #pragma unroll
    for (int off = 1; off < 64; off <<= 1) s += __shfl_xor(s, off);
    const float inv = 1.f / s;

    unsigned short* o = probs + row * 1024 + lane * 16;
    short8 o0 = {0,0,0,0,0,0,0,0}, o1 = {0,0,0,0,0,0,0,0};
    if (act) {
        #pragma unroll
        for (int k = 0; k < 8; ++k) {
            o0[k] = (short)f2bf(x[k] * inv);
            o1[k] = (short)f2bf(x[k + 8] * inv);
        }
    }
    *(short8*)(o)     = o0;
    *(short8*)(o + 8) = o1;
}

// ---------------------------------------------------------------------------
// UbarT[b] = sum_h UT[b*4+h]; 8 elems/thread.
// ---------------------------------------------------------------------------
__global__ __launch_bounds__(256)
void mean_heads(const unsigned short* __restrict__ UT, unsigned short* __restrict__ Ub)
{
    const long per = 1024L * 512;
    long e = ((long)blockIdx.x * 256 + threadIdx.x) * 8;
    long b = e / per; long r = e - b * per;
    const short8 v0 = *(const short8*)(UT + (b * 4 + 0) * per + r);
    const short8 v1 = *(const short8*)(UT + (b * 4 + 1) * per + r);
    const short8 v2 = *(const short8*)(UT + (b * 4 + 2) * per + r);
    const short8 v3 = *(const short8*)(UT + (b * 4 + 3) * per + r);
    short8 o;
    #pragma unroll
    for (int k = 0; k < 8; ++k) {
        float s = bf2f((unsigned short)v0[k]) + bf2f((unsigned short)v1[k])
                + bf2f((unsigned short)v2[k]) + bf2f((unsigned short)v3[k]);
        o[k] = (short)f2bf(s);
    }
    *(short8*)(Ub + b * per + r) = o;
}

// ---------------------------------------------------------------------------
extern "C" void kernel_launch(void* const* d_in, const int* in_sizes, int n_in,
                              void* d_out, int out_size, void* d_ws, size_t ws_size,
                              hipStream_t stream)
{
    const float* emb     = (const float*)d_in[0];  // [4][4096][512]
    const float* emb_all = (const float*)d_in[1];  // [4][4096][960]
    const float* Wq      = (const float*)d_in[2];  // [4][512][512]
    const float* Wk      = (const float*)d_in[3];  // [4][960][960]
    const float* Wv      = (const float*)d_in[4];  // [4][960][960]
    const float* Wo      = (const float*)d_in[5];  // [512][512]
    float* out = (float*)d_out;

    char* ws = (char*)d_ws;
    unsigned short* embT     = (unsigned short*)(ws);              // [b][512][4096]
    unsigned short* emb_allT = (unsigned short*)(ws + 16777216);   // [b][1024][4096]
    unsigned short* emb_allB = (unsigned short*)(ws + 50331648);   // [b][4096][960]
    unsigned short* WqB      = (unsigned short*)(ws + 81788928);   // [h][512][512]
    unsigned short* WkB      = (unsigned short*)(ws + 83886080);   // [h][1024][960]
    unsigned short* WvT      = (unsigned short*)(ws + 91750400);   // [h][1024][960]
    unsigned short* WoB      = (unsigned short*)(ws + 99614720);   // [512][512]
    unsigned short* GT       = (unsigned short*)(ws + 100139008);  // [b][1024][512]
    unsigned short* probs    = (unsigned short*)(ws + 104333312);  // [z][512][1024]
    float2* sc_part          = (float2*)(ws + 121110528);          // [16][32]
    unsigned short* partK    = (unsigned short*)(ws + 134217728);  // 16 MB bf16

    // region reuse (sequential liveness)
    unsigned short* S1  = embT;
    unsigned short* SC  = emb_allT;
    unsigned short* UT  = (unsigned short*)(ws + 33554432);
    unsigned short* UbT = GT;
    unsigned short* W2  = embT;

    // ---- 0. all preps, one launch ----
    prep_all<<<12224, 256, 0, stream>>>(emb, emb_all, Wq, Wk, Wv, Wo,
                                        embT, emb_allT, emb_allB, WqB, WkB, WvT, WoB);

    // ---- 1. split-K (z = b*4+sp): partK[z] = emb_allT chunk x embT chunk^T ----
    gemm_bt<unsigned short, false><<<dim3(4, 8, 16), 512, 0, stream>>>(
        emb_allT, embT, partK, nullptr, 1024, 4096, 4096, 512,
        1024L*4096, 1024, 512L*4096, 1024, 1024L*512, 4, 1.f);
    reduce_gt<<<1024, 256, 0, stream>>>(partK, GT);

    // ---- 2. S1[b,h] = Wq[h] x GT[b]^T  (M=512, N=1024, K=512) ----
    gemm_bt<unsigned short, false><<<dim3(8, 4, 16), 512, 0, stream>>>(
        WqB, GT, S1, nullptr, 512, 512, 512, 1024,
        0, 512L*512, 1024L*512, 0, 512L*1024, 4, 1.f);

    // ---- 3. SC[z] = S1[z] x WkB[h]^T (bf16 out) + fused stats partials ----
    gemm_bt<unsigned short, true><<<dim3(8, 4, 16), 512, 0, stream>>>(
        S1, WkB, SC, sc_part, 960, 1024, 960, 1024,
        4L*512*1024, 512L*1024, 0, 1024L*960, 512L*1024, 4, 1.f);

    // ---- 4. fused instance-norm + softmax (wave-per-row) ----
    norm_softmax<<<2048, 256, 0, stream>>>(SC, sc_part, probs);

    // ---- 5. UT[z] = WvT[h] x probs[z]^T * 0.25  (M=1024, N=512, K=960) ----
    gemm_bt<unsigned short, false><<<dim3(4, 8, 16), 512, 0, stream>>>(
        WvT, probs, UT, nullptr, 960, 960, 1024, 512,
        0, 1024L*960, 4L*512*1024, 512L*1024, 1024L*512, 4, 0.25f);

    // ---- 6. UbT[b] = sum_h UT[b,h] ----
    mean_heads<<<1024, 256, 0, stream>>>(UT, UbT);

    // ---- 7. W2[b] = WoB x UbT[b]^T  (M=512, N=1024, K=512) ----
    gemm_bt<unsigned short, false><<<dim3(8, 4, 4), 512, 0, stream>>>(
        WoB, UbT, W2, nullptr, 512, 512, 512, 1024,
        0, 0, 1024L*512, 0, 512L*1024, 1, 1.f);

    // ---- 8. out[b] = emb_allB[b] x W2[b]^T  (M=4096, N=512, K=960) ----
    gemm_bt<float, false><<<dim3(4, 32, 4), 512, 0, stream>>>(
        emb_allB, W2, out, nullptr, 960, 960, 1024, 512,
        4096L*960, 0, 512L*1024, 0, 4096L*512, 1, 1.f);
}